// Round 1
// 240.137 us; speedup vs baseline: 1.0288x; 1.0288x over previous
//
#include <hip/hip_runtime.h>
#include <hip/hip_bf16.h>
#include <stdint.h>

// ---------------------------------------------------------------------------
// PairRepulsionSwitch: per-edge ZBL + r^-12 repulsion, quarter-summed to both
// endpoint nodes.
//
// R1-R9: atomics rate-limit (655us) -> binning (373) -> LDS sort (327) ->
//   multipass LDS accum (273) -> split energy/accum (252; accum 78us,
//   ~90us fixed harness overhead identified).
// R10: species trick + 8B packed records halved accum traffic.
// R11: clamp accum scan to n_edges (padding never decoded). accum 77us.
// R12: accum counters showed NO saturated pipe (HBM 14.8%, VALU 21.6%,
//   occ 43.6%) -> issue/latency bound, dominated by P=8 replication
//   (51.2M decodes / 410MB L2 re-reads for 12.8M real adds). Move to
//   100KB *dynamic* LDS accumulator (hipFuncSetAttribute opt-in):
//   NR=25600, 1024 thr, P=4, S=64 -> grid=256 (exactly 1 blk/CU, 16
//   waves). Halves all per-record issued work + re-read traffic; partial
//   matrix 96->64 rows. Old 50KB static path kept as fallback if the
//   LDS attribute opt-in fails.
// ---------------------------------------------------------------------------

#define KE_CONST 14.3996454784255f
constexpr float INV_AC = 1.0f / (0.88534f * 0.52917721092f);

#define NR 12800             // fallback path: nodes per range (50 KB static)
#define NRB 25600            // big path: nodes per range (100 KB dynamic LDS)
#define PT_MAX 256           // max n_elem^2 pair-table entries

// ---------------------------------------------------------------- shared math
// c.x = KE*Zi*Zj*SCALE, c.y = (Zi^0.23 + Zj^0.23) * INV_AC
__device__ __forceinline__ float edge_energy_pt(float len, float2 c,
                                                float inv_rmax) {
    float r = fmaxf(len, 0.2f);                 // R_MIN clamp
    float inv_r = 1.0f / r;

    float u = fmaxf(1.0f - r * inv_rmax, 0.0f);
    float u2 = u * u;
    float pc = u2 * u2 * u2;                    // (1-x)^6

    float x = r * c.y;
    float phi = 0.1818f   * __expf(-3.2f    * x)
              + 0.5099f   * __expf(-0.9423f * x)
              + 0.2802f   * __expf(-0.4029f * x)
              + 0.02817f  * __expf(-0.2016f * x);
    float v_zbl = c.x * phi * inv_r * pc;

    float ir2 = inv_r * inv_r;
    float ir4 = ir2 * ir2;
    float ir12 = ir4 * ir4 * ir4;
    float t = fminf(fmaxf((1.5f - r) * 5.0f, 0.0f), 1.0f);
    float sm = t * t * (3.0f - 2.0f * t);
    float v_r12 = 1e-4f * ir12 * pc * sm;

    return 0.25f * (v_zbl + v_r12);
}

__device__ __forceinline__ float edge_energy(float len, float2 zi, float2 zj,
                                             float inv_rmax) {
    float2 c = make_float2(KE_CONST * zi.x * zj.x, (zi.y + zj.y) * INV_AC);
    return edge_energy_pt(len, c, inv_rmax);
}

__device__ __forceinline__ uint16_t f32_to_bf16_rne(float v) {
    uint32_t u = __float_as_uint(v);
    u += 0x7FFFu + ((u >> 16) & 1u);
    return (uint16_t)(u >> 16);
}

// ---------------------------------------------------------------- prep
__global__ void species_kernel(const float* __restrict__ node_attrs,
                               uint8_t* __restrict__ spec,
                               int n_nodes, int n_elem) {
    int i = blockIdx.x * blockDim.x + threadIdx.x;
    if (i >= n_nodes) return;
    float v = 0.0f;
    for (int k = 0; k < n_elem; ++k)
        v += node_attrs[i * n_elem + k] * (float)k;
    spec[i] = (uint8_t)(v + 0.5f);
}

__global__ void pair_kernel(const float* __restrict__ atomic_numbers,
                            float2* __restrict__ ptab, int n_elem) {
    int idx = threadIdx.x;
    int n2 = n_elem * n_elem;
    if (idx >= n2) return;
    int i = idx / n_elem, j = idx % n_elem;
    float Zi = atomic_numbers[i], Zj = atomic_numbers[j];
    ptab[idx] = make_float2(KE_CONST * Zi * Zj,
                            (powf(Zi, 0.23f) + powf(Zj, 0.23f)) * INV_AC);
}

__global__ void prep_nodes_kernel(const float* __restrict__ node_attrs,
                                  const float* __restrict__ atomic_numbers,
                                  float2* __restrict__ ztab,
                                  int n_nodes, int n_elem) {
    int i = blockIdx.x * blockDim.x + threadIdx.x;
    if (i >= n_nodes) return;
    float z = 0.0f;
    for (int k = 0; k < n_elem; ++k)
        z += node_attrs[i * n_elem + k] * atomic_numbers[k];
    ztab[i] = make_float2(z, powf(z, 0.23f));
}

// ------------------------------------------------- energy + pack (8B records)
__global__ __launch_bounds__(256) void energy_pack_kernel(
    const float* __restrict__ lengths,
    const int* __restrict__ src, const int* __restrict__ dst,
    const uint8_t* __restrict__ spec,
    const float2* __restrict__ ptab_g,
    const float* __restrict__ rmax_ptr,
    unsigned long long* __restrict__ recs,
    int n_edges, int total, int n_elem, int nb, int qshift, int vec_ok) {
    __shared__ float2 pt[PT_MAX];
    int tid = threadIdx.x;
    int n2 = n_elem * n_elem;
    for (int i = tid; i < n2; i += 256) pt[i] = ptab_g[i];
    __syncthreads();

    const float inv_rmax = 1.0f / rmax_ptr[0];
    int t = blockIdx.x * blockDim.x + tid;
    int base = t * 4;
    if (base >= total) return;
    int nb2 = 2 * nb;

    if (vec_ok && base + 3 < n_edges) {
        float4 L  = *reinterpret_cast<const float4*>(lengths + base);
        int4   S4 = *reinterpret_cast<const int4*>(src + base);
        int4   D4 = *reinterpret_cast<const int4*>(dst + base);
        int sv[4] = {S4.x, S4.y, S4.z, S4.w};
        int dv[4] = {D4.x, D4.y, D4.z, D4.w};
        float lv[4] = {L.x, L.y, L.z, L.w};
        int spi[4], spj[4];
#pragma unroll
        for (int k = 0; k < 4; ++k) {
            spi[k] = spec[sv[k]];
            spj[k] = spec[dv[k]];
        }
        unsigned long long rv[4];
#pragma unroll
        for (int k = 0; k < 4; ++k) {
            float2 c = pt[spi[k] * n_elem + spj[k]];
            float q = edge_energy_pt(lv[k], c, inv_rmax);
            uint32_t qu = __float_as_uint(q) >> qshift;
            rv[k] = (unsigned long long)(unsigned)sv[k]
                  | ((unsigned long long)(unsigned)dv[k] << nb)
                  | ((unsigned long long)qu << nb2);
        }
        uint4* out = reinterpret_cast<uint4*>(recs + base);
        out[0] = make_uint4((uint32_t)rv[0], (uint32_t)(rv[0] >> 32),
                            (uint32_t)rv[1], (uint32_t)(rv[1] >> 32));
        out[1] = make_uint4((uint32_t)rv[2], (uint32_t)(rv[2] >> 32),
                            (uint32_t)rv[3], (uint32_t)(rv[3] >> 32));
    } else {
        for (int k = 0; k < 4; ++k) {
            int e = base + k;
            if (e >= total) break;
            unsigned long long rec = 0ull;
            if (e < n_edges) {
                int si = src[e], di = dst[e];
                float2 c = pt[spec[si] * n_elem + spec[di]];
                float q = edge_energy_pt(lengths[e], c, inv_rmax);
                uint32_t qu = __float_as_uint(q) >> qshift;
                rec = (unsigned long long)(unsigned)si
                    | ((unsigned long long)(unsigned)di << nb)
                    | ((unsigned long long)qu << (2 * nb));
            }
            recs[e] = rec;
        }
    }
}

// --------------------------------------------------------------- accumulate
__device__ __forceinline__ void accum_rec(
    unsigned long long rec, float* __restrict__ acc,
    unsigned base, unsigned nmask, int nb, int nb2, int qshift, unsigned nr) {
    unsigned sn = (unsigned)rec & nmask;
    unsigned dn = (unsigned)(rec >> nb) & nmask;
    float q = __uint_as_float((uint32_t)(rec >> nb2) << qshift);
    unsigned a = sn - base;
    if (a < nr) atomicAdd(&acc[a], q);
    unsigned b = dn - base;
    if (b < nr) atomicAdd(&acc[b], q);
}

// R12 path: 100KB dynamic LDS, 1024 threads, 1 block/CU (grid = P*S = 256).
__global__ __launch_bounds__(1024) void accum_big_kernel(
    const unsigned long long* __restrict__ recs,
    uint16_t* __restrict__ partial,      // S rows of npad bf16
    int n_edges, int S, int EPB, int npad, int nb, int qshift) {
    extern __shared__ float acc[];
    int tid = threadIdx.x;
    const float4 z4 = make_float4(0.0f, 0.0f, 0.0f, 0.0f);
    for (int i = tid * 4; i < NRB; i += 1024 * 4)
        *reinterpret_cast<float4*>(acc + i) = z4;
    __syncthreads();

    int s = blockIdx.x % S;              // S%8==0: same-s blocks -> same XCD
    int p = blockIdx.x / S;
    const unsigned base = (unsigned)p * NRB;
    const unsigned nmask = (1u << nb) - 1u;
    const int nb2 = 2 * nb;

    int e0 = s * EPB;
    // CLAMP to n_edges (R11): padding records decode to node 0 and would
    // serialize on acc[0] for p==0.
    int e1 = min(e0 + EPB, n_edges);

    for (int off = e0 + tid * 8; off < e1; off += 1024 * 8) {
        if (off + 8 <= e1) {
            uint4 r0 = *reinterpret_cast<const uint4*>(recs + off);
            uint4 r1 = *reinterpret_cast<const uint4*>(recs + off + 2);
            uint4 r2 = *reinterpret_cast<const uint4*>(recs + off + 4);
            uint4 r3 = *reinterpret_cast<const uint4*>(recs + off + 6);
            uint4 rr[4] = {r0, r1, r2, r3};
#pragma unroll
            for (int k = 0; k < 4; ++k) {
                unsigned long long ra = (unsigned long long)rr[k].x
                                      | ((unsigned long long)rr[k].y << 32);
                unsigned long long rb = (unsigned long long)rr[k].z
                                      | ((unsigned long long)rr[k].w << 32);
                accum_rec(ra, acc, base, nmask, nb, nb2, qshift, NRB);
                accum_rec(rb, acc, base, nmask, nb, nb2, qshift, NRB);
            }
        } else {
            for (int e = off; e < e1; ++e)
                accum_rec(recs[e], acc, base, nmask, nb, nb2, qshift, NRB);
        }
    }
    __syncthreads();

    // vectorized bf16 flush: 4 floats -> 8B store
    uint16_t* __restrict__ row = partial + (size_t)s * npad + base;
    for (int i = tid * 4; i < NRB; i += 1024 * 4) {
        float4 v = *reinterpret_cast<const float4*>(acc + i);
        uint32_t w0 = (uint32_t)f32_to_bf16_rne(v.x)
                    | ((uint32_t)f32_to_bf16_rne(v.y) << 16);
        uint32_t w1 = (uint32_t)f32_to_bf16_rne(v.z)
                    | ((uint32_t)f32_to_bf16_rne(v.w) << 16);
        *reinterpret_cast<uint2*>(row + i) = make_uint2(w0, w1);
    }
}

// fallback path (R11): 50KB static LDS, 512 threads, 3 blocks/CU.
__global__ __launch_bounds__(512) void accum_kernel(
    const unsigned long long* __restrict__ recs,
    uint16_t* __restrict__ partial,      // S rows of npad bf16
    int n_edges, int S, int EPB, int npad, int nb, int qshift) {
    __shared__ float acc[NR];
    int tid = threadIdx.x;
    for (int i = tid; i < NR; i += 512) acc[i] = 0.0f;
    __syncthreads();

    int s = blockIdx.x % S;              // S%8==0: same-s blocks -> same XCD
    int p = blockIdx.x / S;
    const unsigned base = (unsigned)p * NR;
    const unsigned nmask = (1u << nb) - 1u;
    const int nb2 = 2 * nb;

    int e0 = s * EPB;
    int e1 = min(e0 + EPB, n_edges);

    for (int off = e0 + tid * 8; off < e1; off += 512 * 8) {
        if (off + 8 <= e1) {
            uint4 r0 = *reinterpret_cast<const uint4*>(recs + off);
            uint4 r1 = *reinterpret_cast<const uint4*>(recs + off + 2);
            uint4 r2 = *reinterpret_cast<const uint4*>(recs + off + 4);
            uint4 r3 = *reinterpret_cast<const uint4*>(recs + off + 6);
            uint4 rr[4] = {r0, r1, r2, r3};
#pragma unroll
            for (int k = 0; k < 4; ++k) {
                unsigned long long ra = (unsigned long long)rr[k].x
                                      | ((unsigned long long)rr[k].y << 32);
                unsigned long long rb = (unsigned long long)rr[k].z
                                      | ((unsigned long long)rr[k].w << 32);
                accum_rec(ra, acc, base, nmask, nb, nb2, qshift, NR);
                accum_rec(rb, acc, base, nmask, nb, nb2, qshift, NR);
            }
        } else {
            for (int e = off; e < e1; ++e)
                accum_rec(recs[e], acc, base, nmask, nb, nb2, qshift, NR);
        }
    }
    __syncthreads();

    uint16_t* __restrict__ row = partial + (size_t)s * npad + base;
    for (int i = tid; i < NR; i += 512)
        row[i] = f32_to_bf16_rne(acc[i]);
}

__global__ void combine_kernel(const uint16_t* __restrict__ partial,
                               float* __restrict__ out,
                               int n_nodes, int S, int npad) {
    int i = blockIdx.x * blockDim.x + threadIdx.x;
    if (i >= n_nodes) return;
    float t = 0.0f;
    for (int s = 0; s < S; ++s) {
        uint32_t h = partial[(size_t)s * npad + i];
        t += __uint_as_float(h << 16);
    }
    out[i] = t;
}

// ----------------------------------------------------------- fallback (R2)
__global__ void zero_out_kernel(float* __restrict__ out, int n) {
    int i = blockIdx.x * blockDim.x + threadIdx.x;
    if (i < n) out[i] = 0.0f;
}

__global__ __launch_bounds__(256) void edge_kernel_atomic(
    const float* __restrict__ lengths,
    const int* __restrict__ src_idx,
    const int* __restrict__ dst_idx,
    const float2* __restrict__ ztab,
    const float* __restrict__ rmax_ptr,
    float* __restrict__ out,
    int n_edges) {
    const float inv_rmax = 1.0f / rmax_ptr[0];
    int t = blockIdx.x * blockDim.x + threadIdx.x;
    int base = t * 4;
    if (base + 3 < n_edges) {
        float4 L = *reinterpret_cast<const float4*>(lengths + base);
        int4 S = *reinterpret_cast<const int4*>(src_idx + base);
        int4 D = *reinterpret_cast<const int4*>(dst_idx + base);
        float l[4] = {L.x, L.y, L.z, L.w};
        int s[4] = {S.x, S.y, S.z, S.w};
        int d[4] = {D.x, D.y, D.z, D.w};
        float2 zs[4], zd[4];
#pragma unroll
        for (int k = 0; k < 4; ++k) { zs[k] = ztab[s[k]]; zd[k] = ztab[d[k]]; }
#pragma unroll
        for (int k = 0; k < 4; ++k) {
            float q = edge_energy(l[k], zs[k], zd[k], inv_rmax);
            unsafeAtomicAdd(&out[s[k]], q);
            unsafeAtomicAdd(&out[d[k]], q);
        }
    } else if (base < n_edges) {
        for (int e = base; e < n_edges; ++e) {
            int si = src_idx[e], di = dst_idx[e];
            float q = edge_energy(lengths[e], ztab[si], ztab[di], inv_rmax);
            unsafeAtomicAdd(&out[si], q);
            unsafeAtomicAdd(&out[di], q);
        }
    }
}

// ---------------------------------------------------------------- launcher
extern "C" void kernel_launch(void* const* d_in, const int* in_sizes, int n_in,
                              void* d_out, int out_size, void* d_ws, size_t ws_size,
                              hipStream_t stream) {
    const float* lengths        = (const float*)d_in[0];
    const float* node_attrs     = (const float*)d_in[1];
    const int*   edge_index     = (const int*)d_in[2];
    const float* atomic_numbers = (const float*)d_in[3];
    const float* rmax_ptr       = (const float*)d_in[4];

    int n_edges = in_sizes[0];
    int n_elem  = in_sizes[3];
    int n_nodes = out_size;
    float* out = (float*)d_out;

    const int* src = edge_index;
    const int* dst = edge_index + n_edges;

    int vec_ok = ((n_edges & 3) == 0) ? 1 : 0;

    // record packing: nb bits per node id, q gets 64-2nb (<=32) bits
    int nb = 1;
    while ((1u << nb) < (unsigned)n_nodes) nb++;
    int qb = 64 - 2 * nb;
    if (qb > 32) qb = 32;
    int qshift = 32 - qb;
    bool pack_ok = (2 * nb + 16 <= 64) && (n_elem * n_elem <= PT_MAX);

    int nb_nodes = (n_nodes + 255) / 256;

    // -------- R12: opt in to 100KB dynamic LDS (once; host-side, capture-safe)
    static int big_ok = -1;
    if (big_ok < 0) {
        big_ok = (hipFuncSetAttribute(
                      reinterpret_cast<const void*>(accum_big_kernel),
                      hipFuncAttributeMaxDynamicSharedMemorySize,
                      NRB * 4) == hipSuccess) ? 1 : 0;
    }

    if (pack_ok && big_ok) {
        int P    = (n_nodes + NRB - 1) / NRB;      // 4 for n_nodes=100K
        int npad = P * NRB;
        // S multiple of 8 (XCD invariant), grid P*S <= 256 (1 blk/CU, 100KB)
        int S = (256 / P) & ~7;
        if (S < 8) S = 8;
        size_t part_off = 0, ptab_off = 0, spec_off = 0, need = 0;
        int EPB = 0, TOTAL = 0;
        for (; S >= 8; S -= 8) {
            EPB = (((n_edges + S - 1) / S) + 4095) & ~4095;   // mult of 4096
            TOTAL = S * EPB;
            part_off = ((size_t)TOTAL * 8 + 255) & ~(size_t)255;
            ptab_off = (part_off + (size_t)S * npad * 2 + 255) & ~(size_t)255;
            spec_off = (ptab_off + (size_t)n_elem * n_elem * 8 + 255) & ~(size_t)255;
            need     = spec_off + (size_t)n_nodes;
            if (need <= ws_size) break;
        }
        if (S >= 8) {
            unsigned long long* recs = (unsigned long long*)d_ws;
            uint16_t* partial = (uint16_t*)((char*)d_ws + part_off);
            float2*   ptab    = (float2*)((char*)d_ws + ptab_off);
            uint8_t*  spec    = (uint8_t*)((char*)d_ws + spec_off);

            species_kernel<<<nb_nodes, 256, 0, stream>>>(
                node_attrs, spec, n_nodes, n_elem);
            pair_kernel<<<1, PT_MAX, 0, stream>>>(atomic_numbers, ptab, n_elem);
            int nb_energy = TOTAL / 1024;     // TOTAL mult of 4096
            energy_pack_kernel<<<nb_energy, 256, 0, stream>>>(
                lengths, src, dst, spec, ptab, rmax_ptr, recs,
                n_edges, TOTAL, n_elem, nb, qshift, vec_ok);
            accum_big_kernel<<<P * S, 1024, NRB * 4, stream>>>(
                recs, partial, n_edges, S, EPB, npad, nb, qshift);
            combine_kernel<<<nb_nodes, 256, 0, stream>>>(
                partial, out, n_nodes, S, npad);
            return;
        }
    }

    // -------- R11 path: 50KB static LDS, 3 blk/CU
    if (pack_ok) {
        int P    = (n_nodes + NR - 1) / NR;
        int npad = P * NR;
        int S = (768 / P) & ~7;
        if (S < 8) S = 8;
        size_t part_off = 0, ptab_off = 0, spec_off = 0, need = 0;
        int EPB = 0, TOTAL = 0;
        for (; S >= 8; S -= 8) {
            EPB = (((n_edges + S - 1) / S) + 4095) & ~4095;   // mult of 4096
            TOTAL = S * EPB;
            part_off = ((size_t)TOTAL * 8 + 255) & ~(size_t)255;
            ptab_off = (part_off + (size_t)S * npad * 2 + 255) & ~(size_t)255;
            spec_off = (ptab_off + (size_t)n_elem * n_elem * 8 + 255) & ~(size_t)255;
            need     = spec_off + (size_t)n_nodes;
            if (need <= ws_size) break;
        }
        if (S >= 8) {
            unsigned long long* recs = (unsigned long long*)d_ws;
            uint16_t* partial = (uint16_t*)((char*)d_ws + part_off);
            float2*   ptab    = (float2*)((char*)d_ws + ptab_off);
            uint8_t*  spec    = (uint8_t*)((char*)d_ws + spec_off);

            species_kernel<<<nb_nodes, 256, 0, stream>>>(
                node_attrs, spec, n_nodes, n_elem);
            pair_kernel<<<1, PT_MAX, 0, stream>>>(atomic_numbers, ptab, n_elem);
            int nb_energy = TOTAL / 1024;
            energy_pack_kernel<<<nb_energy, 256, 0, stream>>>(
                lengths, src, dst, spec, ptab, rmax_ptr, recs,
                n_edges, TOTAL, n_elem, nb, qshift, vec_ok);
            accum_kernel<<<P * S, 512, 0, stream>>>(
                recs, partial, n_edges, S, EPB, npad, nb, qshift);
            combine_kernel<<<nb_nodes, 256, 0, stream>>>(
                partial, out, n_nodes, S, npad);
            return;
        }
    }

    // -------- fallback: replicated-atomic path (R2)
    {
        int stride = ((n_nodes + 49) / 2) * 2;
        int R = 16;
        while (R > 1 &&
               (size_t)R * stride * sizeof(float) + (size_t)n_nodes * sizeof(float2)
                   > ws_size)
            R >>= 1;
        float2* ztab = (float2*)((char*)d_ws + (size_t)R * stride * sizeof(float));
        hipMemsetAsync(d_ws, 0, (size_t)R * stride * sizeof(float), stream);
        prep_nodes_kernel<<<nb_nodes, 256, 0, stream>>>(
            node_attrs, atomic_numbers, ztab, n_nodes, n_elem);
        zero_out_kernel<<<nb_nodes, 256, 0, stream>>>(out, n_nodes);
        int n_thread4 = (n_edges + 3) / 4;
        int nb_edges = (n_thread4 + 255) / 256;
        edge_kernel_atomic<<<nb_edges, 256, 0, stream>>>(
            lengths, src, dst, ztab, rmax_ptr, out, n_edges);
    }
}

// Round 2
// 239.212 us; speedup vs baseline: 1.0328x; 1.0039x over previous
//
#include <hip/hip_runtime.h>
#include <hip/hip_bf16.h>
#include <stdint.h>

// ---------------------------------------------------------------------------
// PairRepulsionSwitch: per-edge ZBL + r^-12 repulsion, quarter-summed to both
// endpoint nodes.
//
// R1-R9: atomics rate-limit (655us) -> binning (373) -> LDS sort (327) ->
//   multipass LDS accum (273) -> split energy/accum (252; accum 78us).
// R10: species trick + 8B packed records halved accum traffic.
// R11: clamp accum scan to n_edges. accum 77us.
// R12: 100KB dynamic LDS accumulator (NRB=25600, 1024thr, P=4, S=64,
//   grid=256 = 1 blk/CU). Halved ALL per-record work + traffic (FETCH
//   70->25MB confirmed) yet dur unchanged at 76.8us, VALUBusy 10.5%,
//   HBM 6%. Time has been ~77us across R9/R11/R12 — invariant only in
//   REAL atomic adds (12.8M). Diagnosis: plain atomicAdd(float*) on LDS
//   compiles to a CAS retry loop (ds_read+ds_cmpst, ~2 dependent LDS
//   round-trips per add) because ds_add_f32 flushes denormals. Latency
//   wall, untouched by traffic reduction.
// R13: unsafeAtomicAdd on the LDS accumulator -> native ds_add_f32
//   (fire-and-forget, no CAS, no lgkmcnt chain). Denorm flush is
//   irrelevant at our magnitudes (partials already bf16-rounded).
// ---------------------------------------------------------------------------

#define KE_CONST 14.3996454784255f
constexpr float INV_AC = 1.0f / (0.88534f * 0.52917721092f);

#define NR 12800             // fallback path: nodes per range (50 KB static)
#define NRB 25600            // big path: nodes per range (100 KB dynamic LDS)
#define PT_MAX 256           // max n_elem^2 pair-table entries

// ---------------------------------------------------------------- shared math
// c.x = KE*Zi*Zj*SCALE, c.y = (Zi^0.23 + Zj^0.23) * INV_AC
__device__ __forceinline__ float edge_energy_pt(float len, float2 c,
                                                float inv_rmax) {
    float r = fmaxf(len, 0.2f);                 // R_MIN clamp
    float inv_r = 1.0f / r;

    float u = fmaxf(1.0f - r * inv_rmax, 0.0f);
    float u2 = u * u;
    float pc = u2 * u2 * u2;                    // (1-x)^6

    float x = r * c.y;
    float phi = 0.1818f   * __expf(-3.2f    * x)
              + 0.5099f   * __expf(-0.9423f * x)
              + 0.2802f   * __expf(-0.4029f * x)
              + 0.02817f  * __expf(-0.2016f * x);
    float v_zbl = c.x * phi * inv_r * pc;

    float ir2 = inv_r * inv_r;
    float ir4 = ir2 * ir2;
    float ir12 = ir4 * ir4 * ir4;
    float t = fminf(fmaxf((1.5f - r) * 5.0f, 0.0f), 1.0f);
    float sm = t * t * (3.0f - 2.0f * t);
    float v_r12 = 1e-4f * ir12 * pc * sm;

    return 0.25f * (v_zbl + v_r12);
}

__device__ __forceinline__ float edge_energy(float len, float2 zi, float2 zj,
                                             float inv_rmax) {
    float2 c = make_float2(KE_CONST * zi.x * zj.x, (zi.y + zj.y) * INV_AC);
    return edge_energy_pt(len, c, inv_rmax);
}

__device__ __forceinline__ uint16_t f32_to_bf16_rne(float v) {
    uint32_t u = __float_as_uint(v);
    u += 0x7FFFu + ((u >> 16) & 1u);
    return (uint16_t)(u >> 16);
}

// ---------------------------------------------------------------- prep
__global__ void species_kernel(const float* __restrict__ node_attrs,
                               uint8_t* __restrict__ spec,
                               int n_nodes, int n_elem) {
    int i = blockIdx.x * blockDim.x + threadIdx.x;
    if (i >= n_nodes) return;
    float v = 0.0f;
    for (int k = 0; k < n_elem; ++k)
        v += node_attrs[i * n_elem + k] * (float)k;
    spec[i] = (uint8_t)(v + 0.5f);
}

__global__ void pair_kernel(const float* __restrict__ atomic_numbers,
                            float2* __restrict__ ptab, int n_elem) {
    int idx = threadIdx.x;
    int n2 = n_elem * n_elem;
    if (idx >= n2) return;
    int i = idx / n_elem, j = idx % n_elem;
    float Zi = atomic_numbers[i], Zj = atomic_numbers[j];
    ptab[idx] = make_float2(KE_CONST * Zi * Zj,
                            (powf(Zi, 0.23f) + powf(Zj, 0.23f)) * INV_AC);
}

__global__ void prep_nodes_kernel(const float* __restrict__ node_attrs,
                                  const float* __restrict__ atomic_numbers,
                                  float2* __restrict__ ztab,
                                  int n_nodes, int n_elem) {
    int i = blockIdx.x * blockDim.x + threadIdx.x;
    if (i >= n_nodes) return;
    float z = 0.0f;
    for (int k = 0; k < n_elem; ++k)
        z += node_attrs[i * n_elem + k] * atomic_numbers[k];
    ztab[i] = make_float2(z, powf(z, 0.23f));
}

// ------------------------------------------------- energy + pack (8B records)
__global__ __launch_bounds__(256) void energy_pack_kernel(
    const float* __restrict__ lengths,
    const int* __restrict__ src, const int* __restrict__ dst,
    const uint8_t* __restrict__ spec,
    const float2* __restrict__ ptab_g,
    const float* __restrict__ rmax_ptr,
    unsigned long long* __restrict__ recs,
    int n_edges, int total, int n_elem, int nb, int qshift, int vec_ok) {
    __shared__ float2 pt[PT_MAX];
    int tid = threadIdx.x;
    int n2 = n_elem * n_elem;
    for (int i = tid; i < n2; i += 256) pt[i] = ptab_g[i];
    __syncthreads();

    const float inv_rmax = 1.0f / rmax_ptr[0];
    int t = blockIdx.x * blockDim.x + tid;
    int base = t * 4;
    if (base >= total) return;
    int nb2 = 2 * nb;

    if (vec_ok && base + 3 < n_edges) {
        float4 L  = *reinterpret_cast<const float4*>(lengths + base);
        int4   S4 = *reinterpret_cast<const int4*>(src + base);
        int4   D4 = *reinterpret_cast<const int4*>(dst + base);
        int sv[4] = {S4.x, S4.y, S4.z, S4.w};
        int dv[4] = {D4.x, D4.y, D4.z, D4.w};
        float lv[4] = {L.x, L.y, L.z, L.w};
        int spi[4], spj[4];
#pragma unroll
        for (int k = 0; k < 4; ++k) {
            spi[k] = spec[sv[k]];
            spj[k] = spec[dv[k]];
        }
        unsigned long long rv[4];
#pragma unroll
        for (int k = 0; k < 4; ++k) {
            float2 c = pt[spi[k] * n_elem + spj[k]];
            float q = edge_energy_pt(lv[k], c, inv_rmax);
            uint32_t qu = __float_as_uint(q) >> qshift;
            rv[k] = (unsigned long long)(unsigned)sv[k]
                  | ((unsigned long long)(unsigned)dv[k] << nb)
                  | ((unsigned long long)qu << nb2);
        }
        uint4* out = reinterpret_cast<uint4*>(recs + base);
        out[0] = make_uint4((uint32_t)rv[0], (uint32_t)(rv[0] >> 32),
                            (uint32_t)rv[1], (uint32_t)(rv[1] >> 32));
        out[1] = make_uint4((uint32_t)rv[2], (uint32_t)(rv[2] >> 32),
                            (uint32_t)rv[3], (uint32_t)(rv[3] >> 32));
    } else {
        for (int k = 0; k < 4; ++k) {
            int e = base + k;
            if (e >= total) break;
            unsigned long long rec = 0ull;
            if (e < n_edges) {
                int si = src[e], di = dst[e];
                float2 c = pt[spec[si] * n_elem + spec[di]];
                float q = edge_energy_pt(lengths[e], c, inv_rmax);
                uint32_t qu = __float_as_uint(q) >> qshift;
                rec = (unsigned long long)(unsigned)si
                    | ((unsigned long long)(unsigned)di << nb)
                    | ((unsigned long long)qu << (2 * nb));
            }
            recs[e] = rec;
        }
    }
}

// --------------------------------------------------------------- accumulate
// R13: unsafeAtomicAdd -> native ds_add_f32 (plain atomicAdd on LDS float
// is a CAS loop: 2 dependent LDS round-trips per successful add).
__device__ __forceinline__ void accum_rec(
    unsigned long long rec, float* __restrict__ acc,
    unsigned base, unsigned nmask, int nb, int nb2, int qshift, unsigned nr) {
    unsigned sn = (unsigned)rec & nmask;
    unsigned dn = (unsigned)(rec >> nb) & nmask;
    float q = __uint_as_float((uint32_t)(rec >> nb2) << qshift);
    unsigned a = sn - base;
    if (a < nr) unsafeAtomicAdd(&acc[a], q);
    unsigned b = dn - base;
    if (b < nr) unsafeAtomicAdd(&acc[b], q);
}

// R12 path: 100KB dynamic LDS, 1024 threads, 1 block/CU (grid = P*S = 256).
__global__ __launch_bounds__(1024) void accum_big_kernel(
    const unsigned long long* __restrict__ recs,
    uint16_t* __restrict__ partial,      // S rows of npad bf16
    int n_edges, int S, int EPB, int npad, int nb, int qshift) {
    extern __shared__ float acc[];
    int tid = threadIdx.x;
    const float4 z4 = make_float4(0.0f, 0.0f, 0.0f, 0.0f);
    for (int i = tid * 4; i < NRB; i += 1024 * 4)
        *reinterpret_cast<float4*>(acc + i) = z4;
    __syncthreads();

    int s = blockIdx.x % S;              // S%8==0: same-s blocks -> same XCD
    int p = blockIdx.x / S;
    const unsigned base = (unsigned)p * NRB;
    const unsigned nmask = (1u << nb) - 1u;
    const int nb2 = 2 * nb;

    int e0 = s * EPB;
    // CLAMP to n_edges (R11): padding records decode to node 0 and would
    // serialize on acc[0] for p==0.
    int e1 = min(e0 + EPB, n_edges);

    for (int off = e0 + tid * 8; off < e1; off += 1024 * 8) {
        if (off + 8 <= e1) {
            uint4 r0 = *reinterpret_cast<const uint4*>(recs + off);
            uint4 r1 = *reinterpret_cast<const uint4*>(recs + off + 2);
            uint4 r2 = *reinterpret_cast<const uint4*>(recs + off + 4);
            uint4 r3 = *reinterpret_cast<const uint4*>(recs + off + 6);
            uint4 rr[4] = {r0, r1, r2, r3};
#pragma unroll
            for (int k = 0; k < 4; ++k) {
                unsigned long long ra = (unsigned long long)rr[k].x
                                      | ((unsigned long long)rr[k].y << 32);
                unsigned long long rb = (unsigned long long)rr[k].z
                                      | ((unsigned long long)rr[k].w << 32);
                accum_rec(ra, acc, base, nmask, nb, nb2, qshift, NRB);
                accum_rec(rb, acc, base, nmask, nb, nb2, qshift, NRB);
            }
        } else {
            for (int e = off; e < e1; ++e)
                accum_rec(recs[e], acc, base, nmask, nb, nb2, qshift, NRB);
        }
    }
    __syncthreads();

    // vectorized bf16 flush: 4 floats -> 8B store
    uint16_t* __restrict__ row = partial + (size_t)s * npad + base;
    for (int i = tid * 4; i < NRB; i += 1024 * 4) {
        float4 v = *reinterpret_cast<const float4*>(acc + i);
        uint32_t w0 = (uint32_t)f32_to_bf16_rne(v.x)
                    | ((uint32_t)f32_to_bf16_rne(v.y) << 16);
        uint32_t w1 = (uint32_t)f32_to_bf16_rne(v.z)
                    | ((uint32_t)f32_to_bf16_rne(v.w) << 16);
        *reinterpret_cast<uint2*>(row + i) = make_uint2(w0, w1);
    }
}

// fallback path (R11): 50KB static LDS, 512 threads, 3 blocks/CU.
__global__ __launch_bounds__(512) void accum_kernel(
    const unsigned long long* __restrict__ recs,
    uint16_t* __restrict__ partial,      // S rows of npad bf16
    int n_edges, int S, int EPB, int npad, int nb, int qshift) {
    __shared__ float acc[NR];
    int tid = threadIdx.x;
    for (int i = tid; i < NR; i += 512) acc[i] = 0.0f;
    __syncthreads();

    int s = blockIdx.x % S;              // S%8==0: same-s blocks -> same XCD
    int p = blockIdx.x / S;
    const unsigned base = (unsigned)p * NR;
    const unsigned nmask = (1u << nb) - 1u;
    const int nb2 = 2 * nb;

    int e0 = s * EPB;
    int e1 = min(e0 + EPB, n_edges);

    for (int off = e0 + tid * 8; off < e1; off += 512 * 8) {
        if (off + 8 <= e1) {
            uint4 r0 = *reinterpret_cast<const uint4*>(recs + off);
            uint4 r1 = *reinterpret_cast<const uint4*>(recs + off + 2);
            uint4 r2 = *reinterpret_cast<const uint4*>(recs + off + 4);
            uint4 r3 = *reinterpret_cast<const uint4*>(recs + off + 6);
            uint4 rr[4] = {r0, r1, r2, r3};
#pragma unroll
            for (int k = 0; k < 4; ++k) {
                unsigned long long ra = (unsigned long long)rr[k].x
                                      | ((unsigned long long)rr[k].y << 32);
                unsigned long long rb = (unsigned long long)rr[k].z
                                      | ((unsigned long long)rr[k].w << 32);
                accum_rec(ra, acc, base, nmask, nb, nb2, qshift, NR);
                accum_rec(rb, acc, base, nmask, nb, nb2, qshift, NR);
            }
        } else {
            for (int e = off; e < e1; ++e)
                accum_rec(recs[e], acc, base, nmask, nb, nb2, qshift, NR);
        }
    }
    __syncthreads();

    uint16_t* __restrict__ row = partial + (size_t)s * npad + base;
    for (int i = tid; i < NR; i += 512)
        row[i] = f32_to_bf16_rne(acc[i]);
}

__global__ void combine_kernel(const uint16_t* __restrict__ partial,
                               float* __restrict__ out,
                               int n_nodes, int S, int npad) {
    int i = blockIdx.x * blockDim.x + threadIdx.x;
    if (i >= n_nodes) return;
    float t = 0.0f;
    for (int s = 0; s < S; ++s) {
        uint32_t h = partial[(size_t)s * npad + i];
        t += __uint_as_float(h << 16);
    }
    out[i] = t;
}

// ----------------------------------------------------------- fallback (R2)
__global__ void zero_out_kernel(float* __restrict__ out, int n) {
    int i = blockIdx.x * blockDim.x + threadIdx.x;
    if (i < n) out[i] = 0.0f;
}

__global__ __launch_bounds__(256) void edge_kernel_atomic(
    const float* __restrict__ lengths,
    const int* __restrict__ src_idx,
    const int* __restrict__ dst_idx,
    const float2* __restrict__ ztab,
    const float* __restrict__ rmax_ptr,
    float* __restrict__ out,
    int n_edges) {
    const float inv_rmax = 1.0f / rmax_ptr[0];
    int t = blockIdx.x * blockDim.x + threadIdx.x;
    int base = t * 4;
    if (base + 3 < n_edges) {
        float4 L = *reinterpret_cast<const float4*>(lengths + base);
        int4 S = *reinterpret_cast<const int4*>(src_idx + base);
        int4 D = *reinterpret_cast<const int4*>(dst_idx + base);
        float l[4] = {L.x, L.y, L.z, L.w};
        int s[4] = {S.x, S.y, S.z, S.w};
        int d[4] = {D.x, D.y, D.z, D.w};
        float2 zs[4], zd[4];
#pragma unroll
        for (int k = 0; k < 4; ++k) { zs[k] = ztab[s[k]]; zd[k] = ztab[d[k]]; }
#pragma unroll
        for (int k = 0; k < 4; ++k) {
            float q = edge_energy(l[k], zs[k], zd[k], inv_rmax);
            unsafeAtomicAdd(&out[s[k]], q);
            unsafeAtomicAdd(&out[d[k]], q);
        }
    } else if (base < n_edges) {
        for (int e = base; e < n_edges; ++e) {
            int si = src_idx[e], di = dst_idx[e];
            float q = edge_energy(lengths[e], ztab[si], ztab[di], inv_rmax);
            unsafeAtomicAdd(&out[si], q);
            unsafeAtomicAdd(&out[di], q);
        }
    }
}

// ---------------------------------------------------------------- launcher
extern "C" void kernel_launch(void* const* d_in, const int* in_sizes, int n_in,
                              void* d_out, int out_size, void* d_ws, size_t ws_size,
                              hipStream_t stream) {
    const float* lengths        = (const float*)d_in[0];
    const float* node_attrs     = (const float*)d_in[1];
    const int*   edge_index     = (const int*)d_in[2];
    const float* atomic_numbers = (const float*)d_in[3];
    const float* rmax_ptr       = (const float*)d_in[4];

    int n_edges = in_sizes[0];
    int n_elem  = in_sizes[3];
    int n_nodes = out_size;
    float* out = (float*)d_out;

    const int* src = edge_index;
    const int* dst = edge_index + n_edges;

    int vec_ok = ((n_edges & 3) == 0) ? 1 : 0;

    // record packing: nb bits per node id, q gets 64-2nb (<=32) bits
    int nb = 1;
    while ((1u << nb) < (unsigned)n_nodes) nb++;
    int qb = 64 - 2 * nb;
    if (qb > 32) qb = 32;
    int qshift = 32 - qb;
    bool pack_ok = (2 * nb + 16 <= 64) && (n_elem * n_elem <= PT_MAX);

    int nb_nodes = (n_nodes + 255) / 256;

    // -------- R12: opt in to 100KB dynamic LDS (once; host-side, capture-safe)
    static int big_ok = -1;
    if (big_ok < 0) {
        big_ok = (hipFuncSetAttribute(
                      reinterpret_cast<const void*>(accum_big_kernel),
                      hipFuncAttributeMaxDynamicSharedMemorySize,
                      NRB * 4) == hipSuccess) ? 1 : 0;
    }

    if (pack_ok && big_ok) {
        int P    = (n_nodes + NRB - 1) / NRB;      // 4 for n_nodes=100K
        int npad = P * NRB;
        // S multiple of 8 (XCD invariant), grid P*S <= 256 (1 blk/CU, 100KB)
        int S = (256 / P) & ~7;
        if (S < 8) S = 8;
        size_t part_off = 0, ptab_off = 0, spec_off = 0, need = 0;
        int EPB = 0, TOTAL = 0;
        for (; S >= 8; S -= 8) {
            EPB = (((n_edges + S - 1) / S) + 4095) & ~4095;   // mult of 4096
            TOTAL = S * EPB;
            part_off = ((size_t)TOTAL * 8 + 255) & ~(size_t)255;
            ptab_off = (part_off + (size_t)S * npad * 2 + 255) & ~(size_t)255;
            spec_off = (ptab_off + (size_t)n_elem * n_elem * 8 + 255) & ~(size_t)255;
            need     = spec_off + (size_t)n_nodes;
            if (need <= ws_size) break;
        }
        if (S >= 8) {
            unsigned long long* recs = (unsigned long long*)d_ws;
            uint16_t* partial = (uint16_t*)((char*)d_ws + part_off);
            float2*   ptab    = (float2*)((char*)d_ws + ptab_off);
            uint8_t*  spec    = (uint8_t*)((char*)d_ws + spec_off);

            species_kernel<<<nb_nodes, 256, 0, stream>>>(
                node_attrs, spec, n_nodes, n_elem);
            pair_kernel<<<1, PT_MAX, 0, stream>>>(atomic_numbers, ptab, n_elem);
            int nb_energy = TOTAL / 1024;     // TOTAL mult of 4096
            energy_pack_kernel<<<nb_energy, 256, 0, stream>>>(
                lengths, src, dst, spec, ptab, rmax_ptr, recs,
                n_edges, TOTAL, n_elem, nb, qshift, vec_ok);
            accum_big_kernel<<<P * S, 1024, NRB * 4, stream>>>(
                recs, partial, n_edges, S, EPB, npad, nb, qshift);
            combine_kernel<<<nb_nodes, 256, 0, stream>>>(
                partial, out, n_nodes, S, npad);
            return;
        }
    }

    // -------- R11 path: 50KB static LDS, 3 blk/CU
    if (pack_ok) {
        int P    = (n_nodes + NR - 1) / NR;
        int npad = P * NR;
        int S = (768 / P) & ~7;
        if (S < 8) S = 8;
        size_t part_off = 0, ptab_off = 0, spec_off = 0, need = 0;
        int EPB = 0, TOTAL = 0;
        for (; S >= 8; S -= 8) {
            EPB = (((n_edges + S - 1) / S) + 4095) & ~4095;   // mult of 4096
            TOTAL = S * EPB;
            part_off = ((size_t)TOTAL * 8 + 255) & ~(size_t)255;
            ptab_off = (part_off + (size_t)S * npad * 2 + 255) & ~(size_t)255;
            spec_off = (ptab_off + (size_t)n_elem * n_elem * 8 + 255) & ~(size_t)255;
            need     = spec_off + (size_t)n_nodes;
            if (need <= ws_size) break;
        }
        if (S >= 8) {
            unsigned long long* recs = (unsigned long long*)d_ws;
            uint16_t* partial = (uint16_t*)((char*)d_ws + part_off);
            float2*   ptab    = (float2*)((char*)d_ws + ptab_off);
            uint8_t*  spec    = (uint8_t*)((char*)d_ws + spec_off);

            species_kernel<<<nb_nodes, 256, 0, stream>>>(
                node_attrs, spec, n_nodes, n_elem);
            pair_kernel<<<1, PT_MAX, 0, stream>>>(atomic_numbers, ptab, n_elem);
            int nb_energy = TOTAL / 1024;
            energy_pack_kernel<<<nb_energy, 256, 0, stream>>>(
                lengths, src, dst, spec, ptab, rmax_ptr, recs,
                n_edges, TOTAL, n_elem, nb, qshift, vec_ok);
            accum_kernel<<<P * S, 512, 0, stream>>>(
                recs, partial, n_edges, S, EPB, npad, nb, qshift);
            combine_kernel<<<nb_nodes, 256, 0, stream>>>(
                partial, out, n_nodes, S, npad);
            return;
        }
    }

    // -------- fallback: replicated-atomic path (R2)
    {
        int stride = ((n_nodes + 49) / 2) * 2;
        int R = 16;
        while (R > 1 &&
               (size_t)R * stride * sizeof(float) + (size_t)n_nodes * sizeof(float2)
                   > ws_size)
            R >>= 1;
        float2* ztab = (float2*)((char*)d_ws + (size_t)R * stride * sizeof(float));
        hipMemsetAsync(d_ws, 0, (size_t)R * stride * sizeof(float), stream);
        prep_nodes_kernel<<<nb_nodes, 256, 0, stream>>>(
            node_attrs, atomic_numbers, ztab, n_nodes, n_elem);
        zero_out_kernel<<<nb_nodes, 256, 0, stream>>>(out, n_nodes);
        int n_thread4 = (n_edges + 3) / 4;
        int nb_edges = (n_thread4 + 255) / 256;
        edge_kernel_atomic<<<nb_edges, 256, 0, stream>>>(
            lengths, src, dst, ztab, rmax_ptr, out, n_edges);
    }
}

// Round 3
// 187.039 us; speedup vs baseline: 1.3209x; 1.2789x over previous
//
#include <hip/hip_runtime.h>
#include <hip/hip_bf16.h>
#include <stdint.h>

// ---------------------------------------------------------------------------
// PairRepulsionSwitch: per-edge ZBL + r^-12 repulsion, quarter-summed to both
// endpoint nodes.
//
// R1-R9: atomics rate-limit (655us) -> binning (373) -> LDS sort (327) ->
//   multipass LDS accum (273) -> split energy/accum (252; accum 78us).
// R10: species trick + 8B packed records halved accum traffic.
// R11: clamp accum scan to n_edges. accum 77us.
// R12: 100KB dynamic LDS acc (P=4,S=64,1024thr, grid=256=1blk/CU). Halved
//   all per-record work + traffic (FETCH 70->25MB) -> dur UNCHANGED 76.8us.
// R13: unsafeAtomicAdd -> null (identical time/VGPRs: hipcc already emits
//   native ds_add_f32 for LDS float atomicAdd; CAS theory dead).
// MODEL (R9/R11/R12/R13): time pinned at ~75-77us = 180K cyc across all
//   structures; only invariant = real atomic lanes (50K/CU) -> 3.6 cy per
//   active LDS f32-atomic lane. R11 vs R12: 2x instr count, same lanes,
//   same time -> cost ~ lanes, not instructions. FP-atomic lane throughput
//   is the wall.
// R14: test dtype-dependence of that wall: fixed-point i32 accumulator
//   (ds_add_u32 = integer bank ALU, possibly bank-parallel vs serialized
//   FP unit). Scale 4096 (quantum 2.4e-4 abs per add, far below the
//   already-passing bf16 partial rounding; worst qi ~8.6e7, slot sums
//   << 2^31; q >= 0 always). Single-variable change on the big path.
// ---------------------------------------------------------------------------

#define KE_CONST 14.3996454784255f
constexpr float INV_AC = 1.0f / (0.88534f * 0.52917721092f);

#define NR 12800             // fallback path: nodes per range (50 KB static)
#define NRB 25600            // big path: nodes per range (100 KB dynamic LDS)
#define PT_MAX 256           // max n_elem^2 pair-table entries

#define QSCALE 4096.0f       // fixed-point scale for i32 LDS accumulation
#define QINV   (1.0f / 4096.0f)

// ---------------------------------------------------------------- shared math
// c.x = KE*Zi*Zj*SCALE, c.y = (Zi^0.23 + Zj^0.23) * INV_AC
__device__ __forceinline__ float edge_energy_pt(float len, float2 c,
                                                float inv_rmax) {
    float r = fmaxf(len, 0.2f);                 // R_MIN clamp
    float inv_r = 1.0f / r;

    float u = fmaxf(1.0f - r * inv_rmax, 0.0f);
    float u2 = u * u;
    float pc = u2 * u2 * u2;                    // (1-x)^6

    float x = r * c.y;
    float phi = 0.1818f   * __expf(-3.2f    * x)
              + 0.5099f   * __expf(-0.9423f * x)
              + 0.2802f   * __expf(-0.4029f * x)
              + 0.02817f  * __expf(-0.2016f * x);
    float v_zbl = c.x * phi * inv_r * pc;

    float ir2 = inv_r * inv_r;
    float ir4 = ir2 * ir2;
    float ir12 = ir4 * ir4 * ir4;
    float t = fminf(fmaxf((1.5f - r) * 5.0f, 0.0f), 1.0f);
    float sm = t * t * (3.0f - 2.0f * t);
    float v_r12 = 1e-4f * ir12 * pc * sm;

    return 0.25f * (v_zbl + v_r12);
}

__device__ __forceinline__ float edge_energy(float len, float2 zi, float2 zj,
                                             float inv_rmax) {
    float2 c = make_float2(KE_CONST * zi.x * zj.x, (zi.y + zj.y) * INV_AC);
    return edge_energy_pt(len, c, inv_rmax);
}

__device__ __forceinline__ uint16_t f32_to_bf16_rne(float v) {
    uint32_t u = __float_as_uint(v);
    u += 0x7FFFu + ((u >> 16) & 1u);
    return (uint16_t)(u >> 16);
}

// ---------------------------------------------------------------- prep
__global__ void species_kernel(const float* __restrict__ node_attrs,
                               uint8_t* __restrict__ spec,
                               int n_nodes, int n_elem) {
    int i = blockIdx.x * blockDim.x + threadIdx.x;
    if (i >= n_nodes) return;
    float v = 0.0f;
    for (int k = 0; k < n_elem; ++k)
        v += node_attrs[i * n_elem + k] * (float)k;
    spec[i] = (uint8_t)(v + 0.5f);
}

__global__ void pair_kernel(const float* __restrict__ atomic_numbers,
                            float2* __restrict__ ptab, int n_elem) {
    int idx = threadIdx.x;
    int n2 = n_elem * n_elem;
    if (idx >= n2) return;
    int i = idx / n_elem, j = idx % n_elem;
    float Zi = atomic_numbers[i], Zj = atomic_numbers[j];
    ptab[idx] = make_float2(KE_CONST * Zi * Zj,
                            (powf(Zi, 0.23f) + powf(Zj, 0.23f)) * INV_AC);
}

__global__ void prep_nodes_kernel(const float* __restrict__ node_attrs,
                                  const float* __restrict__ atomic_numbers,
                                  float2* __restrict__ ztab,
                                  int n_nodes, int n_elem) {
    int i = blockIdx.x * blockDim.x + threadIdx.x;
    if (i >= n_nodes) return;
    float z = 0.0f;
    for (int k = 0; k < n_elem; ++k)
        z += node_attrs[i * n_elem + k] * atomic_numbers[k];
    ztab[i] = make_float2(z, powf(z, 0.23f));
}

// ------------------------------------------------- energy + pack (8B records)
__global__ __launch_bounds__(256) void energy_pack_kernel(
    const float* __restrict__ lengths,
    const int* __restrict__ src, const int* __restrict__ dst,
    const uint8_t* __restrict__ spec,
    const float2* __restrict__ ptab_g,
    const float* __restrict__ rmax_ptr,
    unsigned long long* __restrict__ recs,
    int n_edges, int total, int n_elem, int nb, int qshift, int vec_ok) {
    __shared__ float2 pt[PT_MAX];
    int tid = threadIdx.x;
    int n2 = n_elem * n_elem;
    for (int i = tid; i < n2; i += 256) pt[i] = ptab_g[i];
    __syncthreads();

    const float inv_rmax = 1.0f / rmax_ptr[0];
    int t = blockIdx.x * blockDim.x + tid;
    int base = t * 4;
    if (base >= total) return;
    int nb2 = 2 * nb;

    if (vec_ok && base + 3 < n_edges) {
        float4 L  = *reinterpret_cast<const float4*>(lengths + base);
        int4   S4 = *reinterpret_cast<const int4*>(src + base);
        int4   D4 = *reinterpret_cast<const int4*>(dst + base);
        int sv[4] = {S4.x, S4.y, S4.z, S4.w};
        int dv[4] = {D4.x, D4.y, D4.z, D4.w};
        float lv[4] = {L.x, L.y, L.z, L.w};
        int spi[4], spj[4];
#pragma unroll
        for (int k = 0; k < 4; ++k) {
            spi[k] = spec[sv[k]];
            spj[k] = spec[dv[k]];
        }
        unsigned long long rv[4];
#pragma unroll
        for (int k = 0; k < 4; ++k) {
            float2 c = pt[spi[k] * n_elem + spj[k]];
            float q = edge_energy_pt(lv[k], c, inv_rmax);
            uint32_t qu = __float_as_uint(q) >> qshift;
            rv[k] = (unsigned long long)(unsigned)sv[k]
                  | ((unsigned long long)(unsigned)dv[k] << nb)
                  | ((unsigned long long)qu << nb2);
        }
        uint4* out = reinterpret_cast<uint4*>(recs + base);
        out[0] = make_uint4((uint32_t)rv[0], (uint32_t)(rv[0] >> 32),
                            (uint32_t)rv[1], (uint32_t)(rv[1] >> 32));
        out[1] = make_uint4((uint32_t)rv[2], (uint32_t)(rv[2] >> 32),
                            (uint32_t)rv[3], (uint32_t)(rv[3] >> 32));
    } else {
        for (int k = 0; k < 4; ++k) {
            int e = base + k;
            if (e >= total) break;
            unsigned long long rec = 0ull;
            if (e < n_edges) {
                int si = src[e], di = dst[e];
                float2 c = pt[spec[si] * n_elem + spec[di]];
                float q = edge_energy_pt(lengths[e], c, inv_rmax);
                uint32_t qu = __float_as_uint(q) >> qshift;
                rec = (unsigned long long)(unsigned)si
                    | ((unsigned long long)(unsigned)di << nb)
                    | ((unsigned long long)qu << (2 * nb));
            }
            recs[e] = rec;
        }
    }
}

// --------------------------------------------------------------- accumulate
// R14: fixed-point i32 accumulation -> ds_add_u32 (integer bank ALU).
__device__ __forceinline__ void accum_rec_i(
    unsigned long long rec, int* __restrict__ acc,
    unsigned base, unsigned nmask, int nb, int nb2, int qshift, unsigned nr) {
    unsigned sn = (unsigned)rec & nmask;
    unsigned dn = (unsigned)(rec >> nb) & nmask;
    float q = __uint_as_float((uint32_t)(rec >> nb2) << qshift);
    int qi = __float2int_rn(q * QSCALE);        // q >= 0 always
    unsigned a = sn - base;
    if (a < nr) atomicAdd(&acc[a], qi);
    unsigned b = dn - base;
    if (b < nr) atomicAdd(&acc[b], qi);
}

// f32 variant (fallback path).
__device__ __forceinline__ void accum_rec(
    unsigned long long rec, float* __restrict__ acc,
    unsigned base, unsigned nmask, int nb, int nb2, int qshift, unsigned nr) {
    unsigned sn = (unsigned)rec & nmask;
    unsigned dn = (unsigned)(rec >> nb) & nmask;
    float q = __uint_as_float((uint32_t)(rec >> nb2) << qshift);
    unsigned a = sn - base;
    if (a < nr) atomicAdd(&acc[a], q);
    unsigned b = dn - base;
    if (b < nr) atomicAdd(&acc[b], q);
}

// R12 path: 100KB dynamic LDS, 1024 threads, 1 block/CU (grid = P*S = 256).
__global__ __launch_bounds__(1024) void accum_big_kernel(
    const unsigned long long* __restrict__ recs,
    uint16_t* __restrict__ partial,      // S rows of npad bf16
    int n_edges, int S, int EPB, int npad, int nb, int qshift) {
    extern __shared__ int acc[];
    int tid = threadIdx.x;
    const int4 z4 = make_int4(0, 0, 0, 0);
    for (int i = tid * 4; i < NRB; i += 1024 * 4)
        *reinterpret_cast<int4*>(acc + i) = z4;
    __syncthreads();

    int s = blockIdx.x % S;              // S%8==0: same-s blocks -> same XCD
    int p = blockIdx.x / S;
    const unsigned base = (unsigned)p * NRB;
    const unsigned nmask = (1u << nb) - 1u;
    const int nb2 = 2 * nb;

    int e0 = s * EPB;
    // CLAMP to n_edges (R11): padding records decode to node 0 and would
    // serialize on acc[0] for p==0.
    int e1 = min(e0 + EPB, n_edges);

    for (int off = e0 + tid * 8; off < e1; off += 1024 * 8) {
        if (off + 8 <= e1) {
            uint4 r0 = *reinterpret_cast<const uint4*>(recs + off);
            uint4 r1 = *reinterpret_cast<const uint4*>(recs + off + 2);
            uint4 r2 = *reinterpret_cast<const uint4*>(recs + off + 4);
            uint4 r3 = *reinterpret_cast<const uint4*>(recs + off + 6);
            uint4 rr[4] = {r0, r1, r2, r3};
#pragma unroll
            for (int k = 0; k < 4; ++k) {
                unsigned long long ra = (unsigned long long)rr[k].x
                                      | ((unsigned long long)rr[k].y << 32);
                unsigned long long rb = (unsigned long long)rr[k].z
                                      | ((unsigned long long)rr[k].w << 32);
                accum_rec_i(ra, acc, base, nmask, nb, nb2, qshift, NRB);
                accum_rec_i(rb, acc, base, nmask, nb, nb2, qshift, NRB);
            }
        } else {
            for (int e = off; e < e1; ++e)
                accum_rec_i(recs[e], acc, base, nmask, nb, nb2, qshift, NRB);
        }
    }
    __syncthreads();

    // vectorized bf16 flush: 4 ints -> f32 -> 8B store
    uint16_t* __restrict__ row = partial + (size_t)s * npad + base;
    for (int i = tid * 4; i < NRB; i += 1024 * 4) {
        int4 v = *reinterpret_cast<const int4*>(acc + i);
        float f0 = (float)v.x * QINV, f1 = (float)v.y * QINV;
        float f2 = (float)v.z * QINV, f3 = (float)v.w * QINV;
        uint32_t w0 = (uint32_t)f32_to_bf16_rne(f0)
                    | ((uint32_t)f32_to_bf16_rne(f1) << 16);
        uint32_t w1 = (uint32_t)f32_to_bf16_rne(f2)
                    | ((uint32_t)f32_to_bf16_rne(f3) << 16);
        *reinterpret_cast<uint2*>(row + i) = make_uint2(w0, w1);
    }
}

// fallback path (R11): 50KB static LDS, 512 threads, 3 blocks/CU.
__global__ __launch_bounds__(512) void accum_kernel(
    const unsigned long long* __restrict__ recs,
    uint16_t* __restrict__ partial,      // S rows of npad bf16
    int n_edges, int S, int EPB, int npad, int nb, int qshift) {
    __shared__ float acc[NR];
    int tid = threadIdx.x;
    for (int i = tid; i < NR; i += 512) acc[i] = 0.0f;
    __syncthreads();

    int s = blockIdx.x % S;              // S%8==0: same-s blocks -> same XCD
    int p = blockIdx.x / S;
    const unsigned base = (unsigned)p * NR;
    const unsigned nmask = (1u << nb) - 1u;
    const int nb2 = 2 * nb;

    int e0 = s * EPB;
    int e1 = min(e0 + EPB, n_edges);

    for (int off = e0 + tid * 8; off < e1; off += 512 * 8) {
        if (off + 8 <= e1) {
            uint4 r0 = *reinterpret_cast<const uint4*>(recs + off);
            uint4 r1 = *reinterpret_cast<const uint4*>(recs + off + 2);
            uint4 r2 = *reinterpret_cast<const uint4*>(recs + off + 4);
            uint4 r3 = *reinterpret_cast<const uint4*>(recs + off + 6);
            uint4 rr[4] = {r0, r1, r2, r3};
#pragma unroll
            for (int k = 0; k < 4; ++k) {
                unsigned long long ra = (unsigned long long)rr[k].x
                                      | ((unsigned long long)rr[k].y << 32);
                unsigned long long rb = (unsigned long long)rr[k].z
                                      | ((unsigned long long)rr[k].w << 32);
                accum_rec(ra, acc, base, nmask, nb, nb2, qshift, NR);
                accum_rec(rb, acc, base, nmask, nb, nb2, qshift, NR);
            }
        } else {
            for (int e = off; e < e1; ++e)
                accum_rec(recs[e], acc, base, nmask, nb, nb2, qshift, NR);
        }
    }
    __syncthreads();

    uint16_t* __restrict__ row = partial + (size_t)s * npad + base;
    for (int i = tid; i < NR; i += 512)
        row[i] = f32_to_bf16_rne(acc[i]);
}

__global__ void combine_kernel(const uint16_t* __restrict__ partial,
                               float* __restrict__ out,
                               int n_nodes, int S, int npad) {
    int i = blockIdx.x * blockDim.x + threadIdx.x;
    if (i >= n_nodes) return;
    float t = 0.0f;
    for (int s = 0; s < S; ++s) {
        uint32_t h = partial[(size_t)s * npad + i];
        t += __uint_as_float(h << 16);
    }
    out[i] = t;
}

// ----------------------------------------------------------- fallback (R2)
__global__ void zero_out_kernel(float* __restrict__ out, int n) {
    int i = blockIdx.x * blockDim.x + threadIdx.x;
    if (i < n) out[i] = 0.0f;
}

__global__ __launch_bounds__(256) void edge_kernel_atomic(
    const float* __restrict__ lengths,
    const int* __restrict__ src_idx,
    const int* __restrict__ dst_idx,
    const float2* __restrict__ ztab,
    const float* __restrict__ rmax_ptr,
    float* __restrict__ out,
    int n_edges) {
    const float inv_rmax = 1.0f / rmax_ptr[0];
    int t = blockIdx.x * blockDim.x + threadIdx.x;
    int base = t * 4;
    if (base + 3 < n_edges) {
        float4 L = *reinterpret_cast<const float4*>(lengths + base);
        int4 S = *reinterpret_cast<const int4*>(src_idx + base);
        int4 D = *reinterpret_cast<const int4*>(dst_idx + base);
        float l[4] = {L.x, L.y, L.z, L.w};
        int s[4] = {S.x, S.y, S.z, S.w};
        int d[4] = {D.x, D.y, D.z, D.w};
        float2 zs[4], zd[4];
#pragma unroll
        for (int k = 0; k < 4; ++k) { zs[k] = ztab[s[k]]; zd[k] = ztab[d[k]]; }
#pragma unroll
        for (int k = 0; k < 4; ++k) {
            float q = edge_energy(l[k], zs[k], zd[k], inv_rmax);
            unsafeAtomicAdd(&out[s[k]], q);
            unsafeAtomicAdd(&out[d[k]], q);
        }
    } else if (base < n_edges) {
        for (int e = base; e < n_edges; ++e) {
            int si = src_idx[e], di = dst_idx[e];
            float q = edge_energy(lengths[e], ztab[si], ztab[di], inv_rmax);
            unsafeAtomicAdd(&out[si], q);
            unsafeAtomicAdd(&out[di], q);
        }
    }
}

// ---------------------------------------------------------------- launcher
extern "C" void kernel_launch(void* const* d_in, const int* in_sizes, int n_in,
                              void* d_out, int out_size, void* d_ws, size_t ws_size,
                              hipStream_t stream) {
    const float* lengths        = (const float*)d_in[0];
    const float* node_attrs     = (const float*)d_in[1];
    const int*   edge_index     = (const int*)d_in[2];
    const float* atomic_numbers = (const float*)d_in[3];
    const float* rmax_ptr       = (const float*)d_in[4];

    int n_edges = in_sizes[0];
    int n_elem  = in_sizes[3];
    int n_nodes = out_size;
    float* out = (float*)d_out;

    const int* src = edge_index;
    const int* dst = edge_index + n_edges;

    int vec_ok = ((n_edges & 3) == 0) ? 1 : 0;

    // record packing: nb bits per node id, q gets 64-2nb (<=32) bits
    int nb = 1;
    while ((1u << nb) < (unsigned)n_nodes) nb++;
    int qb = 64 - 2 * nb;
    if (qb > 32) qb = 32;
    int qshift = 32 - qb;
    bool pack_ok = (2 * nb + 16 <= 64) && (n_elem * n_elem <= PT_MAX);

    int nb_nodes = (n_nodes + 255) / 256;

    // -------- R12: opt in to 100KB dynamic LDS (once; host-side, capture-safe)
    static int big_ok = -1;
    if (big_ok < 0) {
        big_ok = (hipFuncSetAttribute(
                      reinterpret_cast<const void*>(accum_big_kernel),
                      hipFuncAttributeMaxDynamicSharedMemorySize,
                      NRB * 4) == hipSuccess) ? 1 : 0;
    }

    if (pack_ok && big_ok) {
        int P    = (n_nodes + NRB - 1) / NRB;      // 4 for n_nodes=100K
        int npad = P * NRB;
        // S multiple of 8 (XCD invariant), grid P*S <= 256 (1 blk/CU, 100KB)
        int S = (256 / P) & ~7;
        if (S < 8) S = 8;
        size_t part_off = 0, ptab_off = 0, spec_off = 0, need = 0;
        int EPB = 0, TOTAL = 0;
        for (; S >= 8; S -= 8) {
            EPB = (((n_edges + S - 1) / S) + 4095) & ~4095;   // mult of 4096
            TOTAL = S * EPB;
            part_off = ((size_t)TOTAL * 8 + 255) & ~(size_t)255;
            ptab_off = (part_off + (size_t)S * npad * 2 + 255) & ~(size_t)255;
            spec_off = (ptab_off + (size_t)n_elem * n_elem * 8 + 255) & ~(size_t)255;
            need     = spec_off + (size_t)n_nodes;
            if (need <= ws_size) break;
        }
        if (S >= 8) {
            unsigned long long* recs = (unsigned long long*)d_ws;
            uint16_t* partial = (uint16_t*)((char*)d_ws + part_off);
            float2*   ptab    = (float2*)((char*)d_ws + ptab_off);
            uint8_t*  spec    = (uint8_t*)((char*)d_ws + spec_off);

            species_kernel<<<nb_nodes, 256, 0, stream>>>(
                node_attrs, spec, n_nodes, n_elem);
            pair_kernel<<<1, PT_MAX, 0, stream>>>(atomic_numbers, ptab, n_elem);
            int nb_energy = TOTAL / 1024;     // TOTAL mult of 4096
            energy_pack_kernel<<<nb_energy, 256, 0, stream>>>(
                lengths, src, dst, spec, ptab, rmax_ptr, recs,
                n_edges, TOTAL, n_elem, nb, qshift, vec_ok);
            accum_big_kernel<<<P * S, 1024, NRB * 4, stream>>>(
                recs, partial, n_edges, S, EPB, npad, nb, qshift);
            combine_kernel<<<nb_nodes, 256, 0, stream>>>(
                partial, out, n_nodes, S, npad);
            return;
        }
    }

    // -------- R11 path: 50KB static LDS, 3 blk/CU
    if (pack_ok) {
        int P    = (n_nodes + NR - 1) / NR;
        int npad = P * NR;
        int S = (768 / P) & ~7;
        if (S < 8) S = 8;
        size_t part_off = 0, ptab_off = 0, spec_off = 0, need = 0;
        int EPB = 0, TOTAL = 0;
        for (; S >= 8; S -= 8) {
            EPB = (((n_edges + S - 1) / S) + 4095) & ~4095;   // mult of 4096
            TOTAL = S * EPB;
            part_off = ((size_t)TOTAL * 8 + 255) & ~(size_t)255;
            ptab_off = (part_off + (size_t)S * npad * 2 + 255) & ~(size_t)255;
            spec_off = (ptab_off + (size_t)n_elem * n_elem * 8 + 255) & ~(size_t)255;
            need     = spec_off + (size_t)n_nodes;
            if (need <= ws_size) break;
        }
        if (S >= 8) {
            unsigned long long* recs = (unsigned long long*)d_ws;
            uint16_t* partial = (uint16_t*)((char*)d_ws + part_off);
            float2*   ptab    = (float2*)((char*)d_ws + ptab_off);
            uint8_t*  spec    = (uint8_t*)((char*)d_ws + spec_off);

            species_kernel<<<nb_nodes, 256, 0, stream>>>(
                node_attrs, spec, n_nodes, n_elem);
            pair_kernel<<<1, PT_MAX, 0, stream>>>(atomic_numbers, ptab, n_elem);
            int nb_energy = TOTAL / 1024;
            energy_pack_kernel<<<nb_energy, 256, 0, stream>>>(
                lengths, src, dst, spec, ptab, rmax_ptr, recs,
                n_edges, TOTAL, n_elem, nb, qshift, vec_ok);
            accum_kernel<<<P * S, 512, 0, stream>>>(
                recs, partial, n_edges, S, EPB, npad, nb, qshift);
            combine_kernel<<<nb_nodes, 256, 0, stream>>>(
                partial, out, n_nodes, S, npad);
            return;
        }
    }

    // -------- fallback: replicated-atomic path (R2)
    {
        int stride = ((n_nodes + 49) / 2) * 2;
        int R = 16;
        while (R > 1 &&
               (size_t)R * stride * sizeof(float) + (size_t)n_nodes * sizeof(float2)
                   > ws_size)
            R >>= 1;
        float2* ztab = (float2*)((char*)d_ws + (size_t)R * stride * sizeof(float));
        hipMemsetAsync(d_ws, 0, (size_t)R * stride * sizeof(float), stream);
        prep_nodes_kernel<<<nb_nodes, 256, 0, stream>>>(
            node_attrs, atomic_numbers, ztab, n_nodes, n_elem);
        zero_out_kernel<<<nb_nodes, 256, 0, stream>>>(out, n_nodes);
        int n_thread4 = (n_edges + 3) / 4;
        int nb_edges = (n_thread4 + 255) / 256;
        edge_kernel_atomic<<<nb_edges, 256, 0, stream>>>(
            lengths, src, dst, ztab, rmax_ptr, out, n_edges);
    }
}

// Round 5
// 164.170 us; speedup vs baseline: 1.5049x; 1.1393x over previous
//
#include <hip/hip_runtime.h>
#include <hip/hip_bf16.h>
#include <stdint.h>

// ---------------------------------------------------------------------------
// PairRepulsionSwitch: per-edge ZBL + r^-12 repulsion, quarter-summed to both
// endpoint nodes.
//
// R1-R9: atomics rate-limit (655us) -> binning (373) -> LDS sort (327) ->
//   multipass LDS accum (273) -> split energy/accum (252; accum 78us).
// R10: species trick + 8B packed records halved accum traffic.
// R11: clamp accum scan to n_edges. accum 77us.
// R12: 100KB dynamic LDS acc (P=4,S=64,1024thr, grid=256=1blk/CU). Halved
//   all per-record work + traffic -> dur UNCHANGED 76.8us.
// R13: unsafeAtomicAdd -> null (hipcc already emits ds_add_f32).
// R14: WIN. fixed-point i32 accumulator -> ds_add_u32 (integer bank ALU,
//   bank-parallel; f32 LDS atomics serialize ~3.6cy/lane). accum 75 -> <59,
//   total 239 -> 187us. Quantization (scale 4096) passed refcheck.
// R15: pack is now the leader (60us, HBM 19%, VALU 20%, occ 60% — nothing
//   saturated). Theory: 2 random spec[] byte-gathers/edge over a 100KB
//   table miss L1 (32KB) -> ~1 L1 line-fill transaction per gather lane.
//   Fix: persistent pack (256 blks x 1024thr, 1 blk/CU), spec table copied
//   ONCE into dynamic LDS per CU, gathers become ds_read_u8.
// R15b: resubmit — R15 bench died to a container-level infra failure
//   (no pytest/counters). Kernel re-audited: LDS budget 99.7KB < 160KB,
//   all vector accesses 16B-aligned, attribute-fail falls back cleanly.
//   Source unchanged.
// ---------------------------------------------------------------------------

#define KE_CONST 14.3996454784255f
constexpr float INV_AC = 1.0f / (0.88534f * 0.52917721092f);

#define NR 12800             // fallback path: nodes per range (50 KB static)
#define NRB 25600            // big path: nodes per range (100 KB dynamic LDS)
#define PT_MAX 256           // max n_elem^2 pair-table entries
#define LDS_SPEC_MAX 147456  // max dynamic LDS bytes for spec table (144 KB)

#define QSCALE 4096.0f       // fixed-point scale for i32 LDS accumulation
#define QINV   (1.0f / 4096.0f)

// ---------------------------------------------------------------- shared math
// c.x = KE*Zi*Zj*SCALE, c.y = (Zi^0.23 + Zj^0.23) * INV_AC
__device__ __forceinline__ float edge_energy_pt(float len, float2 c,
                                                float inv_rmax) {
    float r = fmaxf(len, 0.2f);                 // R_MIN clamp
    float inv_r = 1.0f / r;

    float u = fmaxf(1.0f - r * inv_rmax, 0.0f);
    float u2 = u * u;
    float pc = u2 * u2 * u2;                    // (1-x)^6

    float x = r * c.y;
    float phi = 0.1818f   * __expf(-3.2f    * x)
              + 0.5099f   * __expf(-0.9423f * x)
              + 0.2802f   * __expf(-0.4029f * x)
              + 0.02817f  * __expf(-0.2016f * x);
    float v_zbl = c.x * phi * inv_r * pc;

    float ir2 = inv_r * inv_r;
    float ir4 = ir2 * ir2;
    float ir12 = ir4 * ir4 * ir4;
    float t = fminf(fmaxf((1.5f - r) * 5.0f, 0.0f), 1.0f);
    float sm = t * t * (3.0f - 2.0f * t);
    float v_r12 = 1e-4f * ir12 * pc * sm;

    return 0.25f * (v_zbl + v_r12);
}

__device__ __forceinline__ float edge_energy(float len, float2 zi, float2 zj,
                                             float inv_rmax) {
    float2 c = make_float2(KE_CONST * zi.x * zj.x, (zi.y + zj.y) * INV_AC);
    return edge_energy_pt(len, c, inv_rmax);
}

__device__ __forceinline__ uint16_t f32_to_bf16_rne(float v) {
    uint32_t u = __float_as_uint(v);
    u += 0x7FFFu + ((u >> 16) & 1u);
    return (uint16_t)(u >> 16);
}

// ---------------------------------------------------------------- prep
__global__ void species_kernel(const float* __restrict__ node_attrs,
                               uint8_t* __restrict__ spec,
                               int n_nodes, int n_elem) {
    int i = blockIdx.x * blockDim.x + threadIdx.x;
    if (i >= n_nodes) return;
    float v = 0.0f;
    for (int k = 0; k < n_elem; ++k)
        v += node_attrs[i * n_elem + k] * (float)k;
    spec[i] = (uint8_t)(v + 0.5f);
}

__global__ void pair_kernel(const float* __restrict__ atomic_numbers,
                            float2* __restrict__ ptab, int n_elem) {
    int idx = threadIdx.x;
    int n2 = n_elem * n_elem;
    if (idx >= n2) return;
    int i = idx / n_elem, j = idx % n_elem;
    float Zi = atomic_numbers[i], Zj = atomic_numbers[j];
    ptab[idx] = make_float2(KE_CONST * Zi * Zj,
                            (powf(Zi, 0.23f) + powf(Zj, 0.23f)) * INV_AC);
}

__global__ void prep_nodes_kernel(const float* __restrict__ node_attrs,
                                  const float* __restrict__ atomic_numbers,
                                  float2* __restrict__ ztab,
                                  int n_nodes, int n_elem) {
    int i = blockIdx.x * blockDim.x + threadIdx.x;
    if (i >= n_nodes) return;
    float z = 0.0f;
    for (int k = 0; k < n_elem; ++k)
        z += node_attrs[i * n_elem + k] * atomic_numbers[k];
    ztab[i] = make_float2(z, powf(z, 0.23f));
}

// --------------------------- R15: persistent pack with spec table in LDS
// 256 blocks x 1024 threads (1 blk/CU). Dynamic LDS = spec table (n_nodes
// bytes, padded to 4). Each block covers a contiguous chunk of edges.
__global__ __launch_bounds__(1024) void energy_pack_lds_kernel(
    const float* __restrict__ lengths,
    const int* __restrict__ src, const int* __restrict__ dst,
    const uint8_t* __restrict__ spec,
    const float2* __restrict__ ptab_g,
    const float* __restrict__ rmax_ptr,
    unsigned long long* __restrict__ recs,
    int n_edges, int n_nodes, int n_elem, int nb, int qshift, int chunk) {
    extern __shared__ uint8_t lsp[];     // n_nodes bytes (4B-padded)
    __shared__ float2 pt[PT_MAX];
    int tid = threadIdx.x;

    int n2 = n_elem * n_elem;
    for (int i = tid; i < n2; i += 1024) pt[i] = ptab_g[i];
    // copy spec table to LDS as u32 words (spec region is 4B-padded in ws)
    {
        int nw = (n_nodes + 3) >> 2;
        const uint32_t* s32 = reinterpret_cast<const uint32_t*>(spec);
        uint32_t* l32 = reinterpret_cast<uint32_t*>(lsp);
        for (int i = tid; i < nw; i += 1024) l32[i] = s32[i];
    }
    __syncthreads();

    const float inv_rmax = 1.0f / rmax_ptr[0];
    const int nb2 = 2 * nb;
    int e0 = blockIdx.x * chunk;
    int e1 = min(e0 + chunk, n_edges);

    for (int base = e0 + tid * 4; base < e1; base += 1024 * 4) {
        if (base + 4 <= e1) {            // chunk,e0 are x4 -> base 16B aligned
            float4 L  = *reinterpret_cast<const float4*>(lengths + base);
            int4   S4 = *reinterpret_cast<const int4*>(src + base);
            int4   D4 = *reinterpret_cast<const int4*>(dst + base);
            int sv[4] = {S4.x, S4.y, S4.z, S4.w};
            int dv[4] = {D4.x, D4.y, D4.z, D4.w};
            float lv[4] = {L.x, L.y, L.z, L.w};
            int spi[4], spj[4];
#pragma unroll
            for (int k = 0; k < 4; ++k) {       // LDS gathers (ds_read_u8)
                spi[k] = lsp[sv[k]];
                spj[k] = lsp[dv[k]];
            }
            unsigned long long rv[4];
#pragma unroll
            for (int k = 0; k < 4; ++k) {
                float2 c = pt[spi[k] * n_elem + spj[k]];
                float q = edge_energy_pt(lv[k], c, inv_rmax);
                uint32_t qu = __float_as_uint(q) >> qshift;
                rv[k] = (unsigned long long)(unsigned)sv[k]
                      | ((unsigned long long)(unsigned)dv[k] << nb)
                      | ((unsigned long long)qu << nb2);
            }
            uint4* outp = reinterpret_cast<uint4*>(recs + base);
            outp[0] = make_uint4((uint32_t)rv[0], (uint32_t)(rv[0] >> 32),
                                 (uint32_t)rv[1], (uint32_t)(rv[1] >> 32));
            outp[1] = make_uint4((uint32_t)rv[2], (uint32_t)(rv[2] >> 32),
                                 (uint32_t)rv[3], (uint32_t)(rv[3] >> 32));
        } else {
            for (int e = base; e < e1; ++e) {
                int si = src[e], di = dst[e];
                float2 c = pt[lsp[si] * n_elem + lsp[di]];
                float q = edge_energy_pt(lengths[e], c, inv_rmax);
                uint32_t qu = __float_as_uint(q) >> qshift;
                recs[e] = (unsigned long long)(unsigned)si
                        | ((unsigned long long)(unsigned)di << nb)
                        | ((unsigned long long)qu << nb2);
            }
        }
    }
}

// ---------------- fallback pack (R10/R11): global spec gathers, zero-pads
__global__ __launch_bounds__(256) void energy_pack_kernel(
    const float* __restrict__ lengths,
    const int* __restrict__ src, const int* __restrict__ dst,
    const uint8_t* __restrict__ spec,
    const float2* __restrict__ ptab_g,
    const float* __restrict__ rmax_ptr,
    unsigned long long* __restrict__ recs,
    int n_edges, int total, int n_elem, int nb, int qshift, int vec_ok) {
    __shared__ float2 pt[PT_MAX];
    int tid = threadIdx.x;
    int n2 = n_elem * n_elem;
    for (int i = tid; i < n2; i += 256) pt[i] = ptab_g[i];
    __syncthreads();

    const float inv_rmax = 1.0f / rmax_ptr[0];
    int t = blockIdx.x * blockDim.x + tid;
    int base = t * 4;
    if (base >= total) return;
    int nb2 = 2 * nb;

    if (vec_ok && base + 3 < n_edges) {
        float4 L  = *reinterpret_cast<const float4*>(lengths + base);
        int4   S4 = *reinterpret_cast<const int4*>(src + base);
        int4   D4 = *reinterpret_cast<const int4*>(dst + base);
        int sv[4] = {S4.x, S4.y, S4.z, S4.w};
        int dv[4] = {D4.x, D4.y, D4.z, D4.w};
        float lv[4] = {L.x, L.y, L.z, L.w};
        int spi[4], spj[4];
#pragma unroll
        for (int k = 0; k < 4; ++k) {
            spi[k] = spec[sv[k]];
            spj[k] = spec[dv[k]];
        }
        unsigned long long rv[4];
#pragma unroll
        for (int k = 0; k < 4; ++k) {
            float2 c = pt[spi[k] * n_elem + spj[k]];
            float q = edge_energy_pt(lv[k], c, inv_rmax);
            uint32_t qu = __float_as_uint(q) >> qshift;
            rv[k] = (unsigned long long)(unsigned)sv[k]
                  | ((unsigned long long)(unsigned)dv[k] << nb)
                  | ((unsigned long long)qu << nb2);
        }
        uint4* out = reinterpret_cast<uint4*>(recs + base);
        out[0] = make_uint4((uint32_t)rv[0], (uint32_t)(rv[0] >> 32),
                            (uint32_t)rv[1], (uint32_t)(rv[1] >> 32));
        out[1] = make_uint4((uint32_t)rv[2], (uint32_t)(rv[2] >> 32),
                            (uint32_t)rv[3], (uint32_t)(rv[3] >> 32));
    } else {
        for (int k = 0; k < 4; ++k) {
            int e = base + k;
            if (e >= total) break;
            unsigned long long rec = 0ull;
            if (e < n_edges) {
                int si = src[e], di = dst[e];
                float2 c = pt[spec[si] * n_elem + spec[di]];
                float q = edge_energy_pt(lengths[e], c, inv_rmax);
                uint32_t qu = __float_as_uint(q) >> qshift;
                rec = (unsigned long long)(unsigned)si
                    | ((unsigned long long)(unsigned)di << nb)
                    | ((unsigned long long)qu << (2 * nb));
            }
            recs[e] = rec;
        }
    }
}

// --------------------------------------------------------------- accumulate
// R14: fixed-point i32 accumulation -> ds_add_u32 (integer bank ALU).
__device__ __forceinline__ void accum_rec_i(
    unsigned long long rec, int* __restrict__ acc,
    unsigned base, unsigned nmask, int nb, int nb2, int qshift, unsigned nr) {
    unsigned sn = (unsigned)rec & nmask;
    unsigned dn = (unsigned)(rec >> nb) & nmask;
    float q = __uint_as_float((uint32_t)(rec >> nb2) << qshift);
    int qi = __float2int_rn(q * QSCALE);        // q >= 0 always
    unsigned a = sn - base;
    if (a < nr) atomicAdd(&acc[a], qi);
    unsigned b = dn - base;
    if (b < nr) atomicAdd(&acc[b], qi);
}

// f32 variant (fallback path).
__device__ __forceinline__ void accum_rec(
    unsigned long long rec, float* __restrict__ acc,
    unsigned base, unsigned nmask, int nb, int nb2, int qshift, unsigned nr) {
    unsigned sn = (unsigned)rec & nmask;
    unsigned dn = (unsigned)(rec >> nb) & nmask;
    float q = __uint_as_float((uint32_t)(rec >> nb2) << qshift);
    unsigned a = sn - base;
    if (a < nr) atomicAdd(&acc[a], q);
    unsigned b = dn - base;
    if (b < nr) atomicAdd(&acc[b], q);
}

// R12 path: 100KB dynamic LDS, 1024 threads, 1 block/CU (grid = P*S = 256).
__global__ __launch_bounds__(1024) void accum_big_kernel(
    const unsigned long long* __restrict__ recs,
    uint16_t* __restrict__ partial,      // S rows of npad bf16
    int n_edges, int S, int EPB, int npad, int nb, int qshift) {
    extern __shared__ int acc[];
    int tid = threadIdx.x;
    const int4 z4 = make_int4(0, 0, 0, 0);
    for (int i = tid * 4; i < NRB; i += 1024 * 4)
        *reinterpret_cast<int4*>(acc + i) = z4;
    __syncthreads();

    int s = blockIdx.x % S;              // S%8==0: same-s blocks -> same XCD
    int p = blockIdx.x / S;
    const unsigned base = (unsigned)p * NRB;
    const unsigned nmask = (1u << nb) - 1u;
    const int nb2 = 2 * nb;

    int e0 = s * EPB;
    // CLAMP to n_edges (R11): padding records are never decoded (and since
    // R15 are not even written).
    int e1 = min(e0 + EPB, n_edges);

    for (int off = e0 + tid * 8; off < e1; off += 1024 * 8) {
        if (off + 8 <= e1) {
            uint4 r0 = *reinterpret_cast<const uint4*>(recs + off);
            uint4 r1 = *reinterpret_cast<const uint4*>(recs + off + 2);
            uint4 r2 = *reinterpret_cast<const uint4*>(recs + off + 4);
            uint4 r3 = *reinterpret_cast<const uint4*>(recs + off + 6);
            uint4 rr[4] = {r0, r1, r2, r3};
#pragma unroll
            for (int k = 0; k < 4; ++k) {
                unsigned long long ra = (unsigned long long)rr[k].x
                                      | ((unsigned long long)rr[k].y << 32);
                unsigned long long rb = (unsigned long long)rr[k].z
                                      | ((unsigned long long)rr[k].w << 32);
                accum_rec_i(ra, acc, base, nmask, nb, nb2, qshift, NRB);
                accum_rec_i(rb, acc, base, nmask, nb, nb2, qshift, NRB);
            }
        } else {
            for (int e = off; e < e1; ++e)
                accum_rec_i(recs[e], acc, base, nmask, nb, nb2, qshift, NRB);
        }
    }
    __syncthreads();

    // vectorized bf16 flush: 4 ints -> f32 -> 8B store
    uint16_t* __restrict__ row = partial + (size_t)s * npad + base;
    for (int i = tid * 4; i < NRB; i += 1024 * 4) {
        int4 v = *reinterpret_cast<const int4*>(acc + i);
        float f0 = (float)v.x * QINV, f1 = (float)v.y * QINV;
        float f2 = (float)v.z * QINV, f3 = (float)v.w * QINV;
        uint32_t w0 = (uint32_t)f32_to_bf16_rne(f0)
                    | ((uint32_t)f32_to_bf16_rne(f1) << 16);
        uint32_t w1 = (uint32_t)f32_to_bf16_rne(f2)
                    | ((uint32_t)f32_to_bf16_rne(f3) << 16);
        *reinterpret_cast<uint2*>(row + i) = make_uint2(w0, w1);
    }
}

// fallback path (R11): 50KB static LDS, 512 threads, 3 blocks/CU.
__global__ __launch_bounds__(512) void accum_kernel(
    const unsigned long long* __restrict__ recs,
    uint16_t* __restrict__ partial,      // S rows of npad bf16
    int n_edges, int S, int EPB, int npad, int nb, int qshift) {
    __shared__ float acc[NR];
    int tid = threadIdx.x;
    for (int i = tid; i < NR; i += 512) acc[i] = 0.0f;
    __syncthreads();

    int s = blockIdx.x % S;              // S%8==0: same-s blocks -> same XCD
    int p = blockIdx.x / S;
    const unsigned base = (unsigned)p * NR;
    const unsigned nmask = (1u << nb) - 1u;
    const int nb2 = 2 * nb;

    int e0 = s * EPB;
    int e1 = min(e0 + EPB, n_edges);

    for (int off = e0 + tid * 8; off < e1; off += 512 * 8) {
        if (off + 8 <= e1) {
            uint4 r0 = *reinterpret_cast<const uint4*>(recs + off);
            uint4 r1 = *reinterpret_cast<const uint4*>(recs + off + 2);
            uint4 r2 = *reinterpret_cast<const uint4*>(recs + off + 4);
            uint4 r3 = *reinterpret_cast<const uint4*>(recs + off + 6);
            uint4 rr[4] = {r0, r1, r2, r3};
#pragma unroll
            for (int k = 0; k < 4; ++k) {
                unsigned long long ra = (unsigned long long)rr[k].x
                                      | ((unsigned long long)rr[k].y << 32);
                unsigned long long rb = (unsigned long long)rr[k].z
                                      | ((unsigned long long)rr[k].w << 32);
                accum_rec(ra, acc, base, nmask, nb, nb2, qshift, NR);
                accum_rec(rb, acc, base, nmask, nb, nb2, qshift, NR);
            }
        } else {
            for (int e = off; e < e1; ++e)
                accum_rec(recs[e], acc, base, nmask, nb, nb2, qshift, NR);
        }
    }
    __syncthreads();

    uint16_t* __restrict__ row = partial + (size_t)s * npad + base;
    for (int i = tid; i < NR; i += 512)
        row[i] = f32_to_bf16_rne(acc[i]);
}

__global__ void combine_kernel(const uint16_t* __restrict__ partial,
                               float* __restrict__ out,
                               int n_nodes, int S, int npad) {
    int i = blockIdx.x * blockDim.x + threadIdx.x;
    if (i >= n_nodes) return;
    float t = 0.0f;
    for (int s = 0; s < S; ++s) {
        uint32_t h = partial[(size_t)s * npad + i];
        t += __uint_as_float(h << 16);
    }
    out[i] = t;
}

// ----------------------------------------------------------- fallback (R2)
__global__ void zero_out_kernel(float* __restrict__ out, int n) {
    int i = blockIdx.x * blockDim.x + threadIdx.x;
    if (i < n) out[i] = 0.0f;
}

__global__ __launch_bounds__(256) void edge_kernel_atomic(
    const float* __restrict__ lengths,
    const int* __restrict__ src_idx,
    const int* __restrict__ dst_idx,
    const float2* __restrict__ ztab,
    const float* __restrict__ rmax_ptr,
    float* __restrict__ out,
    int n_edges) {
    const float inv_rmax = 1.0f / rmax_ptr[0];
    int t = blockIdx.x * blockDim.x + threadIdx.x;
    int base = t * 4;
    if (base + 3 < n_edges) {
        float4 L = *reinterpret_cast<const float4*>(lengths + base);
        int4 S = *reinterpret_cast<const int4*>(src_idx + base);
        int4 D = *reinterpret_cast<const int4*>(dst_idx + base);
        float l[4] = {L.x, L.y, L.z, L.w};
        int s[4] = {S.x, S.y, S.z, S.w};
        int d[4] = {D.x, D.y, D.z, D.w};
        float2 zs[4], zd[4];
#pragma unroll
        for (int k = 0; k < 4; ++k) { zs[k] = ztab[s[k]]; zd[k] = ztab[d[k]]; }
#pragma unroll
        for (int k = 0; k < 4; ++k) {
            float q = edge_energy(l[k], zs[k], zd[k], inv_rmax);
            unsafeAtomicAdd(&out[s[k]], q);
            unsafeAtomicAdd(&out[d[k]], q);
        }
    } else if (base < n_edges) {
        for (int e = base; e < n_edges; ++e) {
            int si = src_idx[e], di = dst_idx[e];
            float q = edge_energy(lengths[e], ztab[si], ztab[di], inv_rmax);
            unsafeAtomicAdd(&out[si], q);
            unsafeAtomicAdd(&out[di], q);
        }
    }
}

// ---------------------------------------------------------------- launcher
extern "C" void kernel_launch(void* const* d_in, const int* in_sizes, int n_in,
                              void* d_out, int out_size, void* d_ws, size_t ws_size,
                              hipStream_t stream) {
    const float* lengths        = (const float*)d_in[0];
    const float* node_attrs     = (const float*)d_in[1];
    const int*   edge_index     = (const int*)d_in[2];
    const float* atomic_numbers = (const float*)d_in[3];
    const float* rmax_ptr       = (const float*)d_in[4];

    int n_edges = in_sizes[0];
    int n_elem  = in_sizes[3];
    int n_nodes = out_size;
    float* out = (float*)d_out;

    const int* src = edge_index;
    const int* dst = edge_index + n_edges;

    int vec_ok = ((n_edges & 3) == 0) ? 1 : 0;

    // record packing: nb bits per node id, q gets 64-2nb (<=32) bits
    int nb = 1;
    while ((1u << nb) < (unsigned)n_nodes) nb++;
    int qb = 64 - 2 * nb;
    if (qb > 32) qb = 32;
    int qshift = 32 - qb;
    bool pack_ok = (2 * nb + 16 <= 64) && (n_elem * n_elem <= PT_MAX);

    int nb_nodes = (n_nodes + 255) / 256;
    int spec_bytes = (n_nodes + 3) & ~3;

    // -------- one-time dynamic-LDS opt-ins (host-side, capture-safe)
    static int big_ok = -1;
    if (big_ok < 0) {
        big_ok = (hipFuncSetAttribute(
                      reinterpret_cast<const void*>(accum_big_kernel),
                      hipFuncAttributeMaxDynamicSharedMemorySize,
                      NRB * 4) == hipSuccess) ? 1 : 0;
    }
    static int pack_lds_ok = -1;
    if (pack_lds_ok < 0) {
        pack_lds_ok = (hipFuncSetAttribute(
                           reinterpret_cast<const void*>(energy_pack_lds_kernel),
                           hipFuncAttributeMaxDynamicSharedMemorySize,
                           LDS_SPEC_MAX) == hipSuccess) ? 1 : 0;
    }
    bool use_lds_pack = pack_lds_ok && (spec_bytes <= LDS_SPEC_MAX);

    if (pack_ok && big_ok) {
        int P    = (n_nodes + NRB - 1) / NRB;      // 4 for n_nodes=100K
        int npad = P * NRB;
        // S multiple of 8 (XCD invariant), grid P*S <= 256 (1 blk/CU, 100KB)
        int S = (256 / P) & ~7;
        if (S < 8) S = 8;
        size_t part_off = 0, ptab_off = 0, spec_off = 0, need = 0;
        int EPB = 0, TOTAL = 0;
        for (; S >= 8; S -= 8) {
            EPB = (((n_edges + S - 1) / S) + 4095) & ~4095;   // mult of 4096
            TOTAL = S * EPB;
            part_off = ((size_t)TOTAL * 8 + 255) & ~(size_t)255;
            ptab_off = (part_off + (size_t)S * npad * 2 + 255) & ~(size_t)255;
            spec_off = (ptab_off + (size_t)n_elem * n_elem * 8 + 255) & ~(size_t)255;
            need     = spec_off + (size_t)spec_bytes;
            if (need <= ws_size) break;
        }
        if (S >= 8) {
            unsigned long long* recs = (unsigned long long*)d_ws;
            uint16_t* partial = (uint16_t*)((char*)d_ws + part_off);
            float2*   ptab    = (float2*)((char*)d_ws + ptab_off);
            uint8_t*  spec    = (uint8_t*)((char*)d_ws + spec_off);

            species_kernel<<<nb_nodes, 256, 0, stream>>>(
                node_attrs, spec, n_nodes, n_elem);
            pair_kernel<<<1, PT_MAX, 0, stream>>>(atomic_numbers, ptab, n_elem);
            if (use_lds_pack) {
                int chunk = (((n_edges + 255) / 256) + 3) & ~3;   // x4
                energy_pack_lds_kernel<<<256, 1024, spec_bytes, stream>>>(
                    lengths, src, dst, spec, ptab, rmax_ptr, recs,
                    n_edges, n_nodes, n_elem, nb, qshift, chunk);
            } else {
                int nb_energy = TOTAL / 1024;     // TOTAL mult of 4096
                energy_pack_kernel<<<nb_energy, 256, 0, stream>>>(
                    lengths, src, dst, spec, ptab, rmax_ptr, recs,
                    n_edges, TOTAL, n_elem, nb, qshift, vec_ok);
            }
            accum_big_kernel<<<P * S, 1024, NRB * 4, stream>>>(
                recs, partial, n_edges, S, EPB, npad, nb, qshift);
            combine_kernel<<<nb_nodes, 256, 0, stream>>>(
                partial, out, n_nodes, S, npad);
            return;
        }
    }

    // -------- R11 path: 50KB static LDS, 3 blk/CU
    if (pack_ok) {
        int P    = (n_nodes + NR - 1) / NR;
        int npad = P * NR;
        int S = (768 / P) & ~7;
        if (S < 8) S = 8;
        size_t part_off = 0, ptab_off = 0, spec_off = 0, need = 0;
        int EPB = 0, TOTAL = 0;
        for (; S >= 8; S -= 8) {
            EPB = (((n_edges + S - 1) / S) + 4095) & ~4095;   // mult of 4096
            TOTAL = S * EPB;
            part_off = ((size_t)TOTAL * 8 + 255) & ~(size_t)255;
            ptab_off = (part_off + (size_t)S * npad * 2 + 255) & ~(size_t)255;
            spec_off = (ptab_off + (size_t)n_elem * n_elem * 8 + 255) & ~(size_t)255;
            need     = spec_off + (size_t)spec_bytes;
            if (need <= ws_size) break;
        }
        if (S >= 8) {
            unsigned long long* recs = (unsigned long long*)d_ws;
            uint16_t* partial = (uint16_t*)((char*)d_ws + part_off);
            float2*   ptab    = (float2*)((char*)d_ws + ptab_off);
            uint8_t*  spec    = (uint8_t*)((char*)d_ws + spec_off);

            species_kernel<<<nb_nodes, 256, 0, stream>>>(
                node_attrs, spec, n_nodes, n_elem);
            pair_kernel<<<1, PT_MAX, 0, stream>>>(atomic_numbers, ptab, n_elem);
            int nb_energy = TOTAL / 1024;
            energy_pack_kernel<<<nb_energy, 256, 0, stream>>>(
                lengths, src, dst, spec, ptab, rmax_ptr, recs,
                n_edges, TOTAL, n_elem, nb, qshift, vec_ok);
            accum_kernel<<<P * S, 512, 0, stream>>>(
                recs, partial, n_edges, S, EPB, npad, nb, qshift);
            combine_kernel<<<nb_nodes, 256, 0, stream>>>(
                partial, out, n_nodes, S, npad);
            return;
        }
    }

    // -------- fallback: replicated-atomic path (R2)
    {
        int stride = ((n_nodes + 49) / 2) * 2;
        int R = 16;
        while (R > 1 &&
               (size_t)R * stride * sizeof(float) + (size_t)n_nodes * sizeof(float2)
                   > ws_size)
            R >>= 1;
        float2* ztab = (float2*)((char*)d_ws + (size_t)R * stride * sizeof(float));
        hipMemsetAsync(d_ws, 0, (size_t)R * stride * sizeof(float), stream);
        prep_nodes_kernel<<<nb_nodes, 256, 0, stream>>>(
            node_attrs, atomic_numbers, ztab, n_nodes, n_elem);
        zero_out_kernel<<<nb_nodes, 256, 0, stream>>>(out, n_nodes);
        int n_thread4 = (n_edges + 3) / 4;
        int nb_edges = (n_thread4 + 255) / 256;
        edge_kernel_atomic<<<nb_edges, 256, 0, stream>>>(
            lengths, src, dst, ztab, rmax_ptr, out, n_edges);
    }
}

// Round 6
// 154.053 us; speedup vs baseline: 1.6037x; 1.0657x over previous
//
#include <hip/hip_runtime.h>
#include <hip/hip_bf16.h>
#include <hip/hip_fp16.h>
#include <stdint.h>

// ---------------------------------------------------------------------------
// PairRepulsionSwitch: per-edge ZBL + r^-12 repulsion, quarter-summed to both
// endpoint nodes.
//
// R1-R9: atomics rate-limit (655us) -> binning -> LDS sort -> multipass LDS
//   accum -> split energy/accum (252us).
// R10/R11: species trick + 8B packed records; clamp scan to n_edges.
// R12: 100KB LDS accumulator, 1 blk/CU. Traffic halved, time unchanged.
// R13: unsafeAtomicAdd null (hipcc already emits ds_add_f32).
// R14: WIN: fixed-point i32 accumulator -> ds_add_u32 is bank-parallel
//   (f32 LDS atomics serialize ~3.6cy/lane). 239 -> 187us.
// R15: WIN: persistent pack, spec table in 100KB LDS (ds_read_u8 gathers
//   instead of per-lane L1-miss line fills). 187 -> 164us. Top dispatch is
//   now the HARNESS's 256MB workspace re-poison fill (40us @6.6TB/s).
// R16: kill the recs round-trip. src/dst are already inputs — packing them
//   into 8B records was redundant. Pack now writes ONLY q as fp16
//   (2B/edge, 12.8MB vs 51.2MB); accum reads src/dst/q directly (int4 +
//   8B half loads, working set ~90MB = L3-resident for the x4 p-block
//   re-reads). NRB -> 32768 pow2 (128KB i32 LDS, still 1 blk/CU).
//   fp16 q rel err 4.9e-4 < bf16-partial err 2e-3 already passing.
// ---------------------------------------------------------------------------

#define KE_CONST 14.3996454784255f
constexpr float INV_AC = 1.0f / (0.88534f * 0.52917721092f);

#define NR 12800             // R11 fallback: nodes per range (50 KB static)
#define NRQ 32768            // R16 path: nodes per range (128 KB i32 LDS)
#define PT_MAX 256           // max n_elem^2 pair-table entries
#define LDS_SPEC_MAX 147456  // max dynamic LDS bytes for spec table (144 KB)

#define QSCALE 4096.0f       // fixed-point scale for i32 LDS accumulation
#define QINV   (1.0f / 4096.0f)

// ---------------------------------------------------------------- shared math
// c.x = KE*Zi*Zj*SCALE, c.y = (Zi^0.23 + Zj^0.23) * INV_AC
__device__ __forceinline__ float edge_energy_pt(float len, float2 c,
                                                float inv_rmax) {
    float r = fmaxf(len, 0.2f);                 // R_MIN clamp
    float inv_r = 1.0f / r;

    float u = fmaxf(1.0f - r * inv_rmax, 0.0f);
    float u2 = u * u;
    float pc = u2 * u2 * u2;                    // (1-x)^6

    float x = r * c.y;
    float phi = 0.1818f   * __expf(-3.2f    * x)
              + 0.5099f   * __expf(-0.9423f * x)
              + 0.2802f   * __expf(-0.4029f * x)
              + 0.02817f  * __expf(-0.2016f * x);
    float v_zbl = c.x * phi * inv_r * pc;

    float ir2 = inv_r * inv_r;
    float ir4 = ir2 * ir2;
    float ir12 = ir4 * ir4 * ir4;
    float t = fminf(fmaxf((1.5f - r) * 5.0f, 0.0f), 1.0f);
    float sm = t * t * (3.0f - 2.0f * t);
    float v_r12 = 1e-4f * ir12 * pc * sm;

    return 0.25f * (v_zbl + v_r12);
}

__device__ __forceinline__ float edge_energy(float len, float2 zi, float2 zj,
                                             float inv_rmax) {
    float2 c = make_float2(KE_CONST * zi.x * zj.x, (zi.y + zj.y) * INV_AC);
    return edge_energy_pt(len, c, inv_rmax);
}

__device__ __forceinline__ uint16_t f32_to_bf16_rne(float v) {
    uint32_t u = __float_as_uint(v);
    u += 0x7FFFu + ((u >> 16) & 1u);
    return (uint16_t)(u >> 16);
}

// ---------------------------------------------------------------- prep
__global__ void species_kernel(const float* __restrict__ node_attrs,
                               uint8_t* __restrict__ spec,
                               int n_nodes, int n_elem) {
    int i = blockIdx.x * blockDim.x + threadIdx.x;
    if (i >= n_nodes) return;
    float v = 0.0f;
    for (int k = 0; k < n_elem; ++k)
        v += node_attrs[i * n_elem + k] * (float)k;
    spec[i] = (uint8_t)(v + 0.5f);
}

__global__ void pair_kernel(const float* __restrict__ atomic_numbers,
                            float2* __restrict__ ptab, int n_elem) {
    int idx = threadIdx.x;
    int n2 = n_elem * n_elem;
    if (idx >= n2) return;
    int i = idx / n_elem, j = idx % n_elem;
    float Zi = atomic_numbers[i], Zj = atomic_numbers[j];
    ptab[idx] = make_float2(KE_CONST * Zi * Zj,
                            (powf(Zi, 0.23f) + powf(Zj, 0.23f)) * INV_AC);
}

__global__ void prep_nodes_kernel(const float* __restrict__ node_attrs,
                                  const float* __restrict__ atomic_numbers,
                                  float2* __restrict__ ztab,
                                  int n_nodes, int n_elem) {
    int i = blockIdx.x * blockDim.x + threadIdx.x;
    if (i >= n_nodes) return;
    float z = 0.0f;
    for (int k = 0; k < n_elem; ++k)
        z += node_attrs[i * n_elem + k] * atomic_numbers[k];
    ztab[i] = make_float2(z, powf(z, 0.23f));
}

// ------------------- R16: persistent energy kernel, spec in LDS, q out fp16
// 256 blocks x 1024 threads (1 blk/CU). Dynamic LDS = spec table.
__global__ __launch_bounds__(1024) void energy_q_lds_kernel(
    const float* __restrict__ lengths,
    const int* __restrict__ src, const int* __restrict__ dst,
    const uint8_t* __restrict__ spec,
    const float2* __restrict__ ptab_g,
    const float* __restrict__ rmax_ptr,
    __half* __restrict__ qout,
    int n_edges, int n_nodes, int n_elem, int chunk) {
    extern __shared__ uint8_t lsp[];     // n_nodes bytes (4B-padded)
    __shared__ float2 pt[PT_MAX];
    int tid = threadIdx.x;

    int n2 = n_elem * n_elem;
    for (int i = tid; i < n2; i += 1024) pt[i] = ptab_g[i];
    {
        int nw = (n_nodes + 3) >> 2;
        const uint32_t* s32 = reinterpret_cast<const uint32_t*>(spec);
        uint32_t* l32 = reinterpret_cast<uint32_t*>(lsp);
        for (int i = tid; i < nw; i += 1024) l32[i] = s32[i];
    }
    __syncthreads();

    const float inv_rmax = 1.0f / rmax_ptr[0];
    int e0 = blockIdx.x * chunk;
    int e1 = min(e0 + chunk, n_edges);

    for (int base = e0 + tid * 4; base < e1; base += 1024 * 4) {
        if (base + 4 <= e1) {            // chunk,e0 mult of 4 -> aligned
            float4 L  = *reinterpret_cast<const float4*>(lengths + base);
            int4   S4 = *reinterpret_cast<const int4*>(src + base);
            int4   D4 = *reinterpret_cast<const int4*>(dst + base);
            int sv[4] = {S4.x, S4.y, S4.z, S4.w};
            int dv[4] = {D4.x, D4.y, D4.z, D4.w};
            float lv[4] = {L.x, L.y, L.z, L.w};
            int spi[4], spj[4];
#pragma unroll
            for (int k = 0; k < 4; ++k) {       // LDS gathers (ds_read_u8)
                spi[k] = lsp[sv[k]];
                spj[k] = lsp[dv[k]];
            }
            float q[4];
#pragma unroll
            for (int k = 0; k < 4; ++k) {
                float2 c = pt[spi[k] * n_elem + spj[k]];
                q[k] = edge_energy_pt(lv[k], c, inv_rmax);
            }
            __half2 h01 = __floats2half2_rn(q[0], q[1]);
            __half2 h23 = __floats2half2_rn(q[2], q[3]);
            uint32_t w0, w1;
            memcpy(&w0, &h01, 4);
            memcpy(&w1, &h23, 4);
            *reinterpret_cast<uint2*>(qout + base) = make_uint2(w0, w1);
        } else {
            for (int e = base; e < e1; ++e) {
                int si = src[e], di = dst[e];
                float2 c = pt[lsp[si] * n_elem + lsp[di]];
                qout[e] = __float2half_rn(edge_energy_pt(lengths[e], c, inv_rmax));
            }
        }
    }
}

// ------------------- R16: accumulate straight from src/dst/q (no records)
// grid = P*S, 1024 threads, dynamic LDS = NRQ i32 (128KB, 1 blk/CU).
__global__ __launch_bounds__(1024) void accum_q_kernel(
    const int* __restrict__ src, const int* __restrict__ dst,
    const __half* __restrict__ qv,
    uint16_t* __restrict__ partial,      // S rows of npad bf16
    int n_edges, int S, int EPB, int npad) {
    extern __shared__ int acc[];
    int tid = threadIdx.x;
    const int4 z4 = make_int4(0, 0, 0, 0);
    for (int i = tid * 4; i < NRQ; i += 1024 * 4)
        *reinterpret_cast<int4*>(acc + i) = z4;
    __syncthreads();

    int s = blockIdx.x % S;              // S%8==0: same-s blocks -> same XCD
    int p = blockIdx.x / S;
    const unsigned base = (unsigned)p * NRQ;

    int e0 = s * EPB;                    // EPB mult of 4096 -> aligned loads
    int e1 = min(e0 + EPB, n_edges);

    for (int off = e0 + tid * 4; off < e1; off += 1024 * 4) {
        if (off + 4 <= e1) {
            int4 S4 = *reinterpret_cast<const int4*>(src + off);
            int4 D4 = *reinterpret_cast<const int4*>(dst + off);
            __half2 h01 = *reinterpret_cast<const __half2*>(qv + off);
            __half2 h23 = *reinterpret_cast<const __half2*>(qv + off + 2);
            float qf[4] = {__low2float(h01), __high2float(h01),
                           __low2float(h23), __high2float(h23)};
            int sv[4] = {S4.x, S4.y, S4.z, S4.w};
            int dv[4] = {D4.x, D4.y, D4.z, D4.w};
#pragma unroll
            for (int k = 0; k < 4; ++k) {
                int qi = __float2int_rn(qf[k] * QSCALE);
                unsigned a = (unsigned)sv[k] - base;
                if (a < NRQ) atomicAdd(&acc[a], qi);
                unsigned b = (unsigned)dv[k] - base;
                if (b < NRQ) atomicAdd(&acc[b], qi);
            }
        } else {
            for (int e = off; e < e1; ++e) {
                int qi = __float2int_rn(__half2float(qv[e]) * QSCALE);
                unsigned a = (unsigned)src[e] - base;
                if (a < NRQ) atomicAdd(&acc[a], qi);
                unsigned b = (unsigned)dst[e] - base;
                if (b < NRQ) atomicAdd(&acc[b], qi);
            }
        }
    }
    __syncthreads();

    // vectorized bf16 flush: 4 ints -> f32 -> 8B store
    uint16_t* __restrict__ row = partial + (size_t)s * npad + base;
    for (int i = tid * 4; i < NRQ; i += 1024 * 4) {
        int4 v = *reinterpret_cast<const int4*>(acc + i);
        float f0 = (float)v.x * QINV, f1 = (float)v.y * QINV;
        float f2 = (float)v.z * QINV, f3 = (float)v.w * QINV;
        uint32_t w0 = (uint32_t)f32_to_bf16_rne(f0)
                    | ((uint32_t)f32_to_bf16_rne(f1) << 16);
        uint32_t w1 = (uint32_t)f32_to_bf16_rne(f2)
                    | ((uint32_t)f32_to_bf16_rne(f3) << 16);
        *reinterpret_cast<uint2*>(row + i) = make_uint2(w0, w1);
    }
}

// ---------------- fallback pack (R10/R11): global spec gathers, 8B records
__global__ __launch_bounds__(256) void energy_pack_kernel(
    const float* __restrict__ lengths,
    const int* __restrict__ src, const int* __restrict__ dst,
    const uint8_t* __restrict__ spec,
    const float2* __restrict__ ptab_g,
    const float* __restrict__ rmax_ptr,
    unsigned long long* __restrict__ recs,
    int n_edges, int total, int n_elem, int nb, int qshift, int vec_ok) {
    __shared__ float2 pt[PT_MAX];
    int tid = threadIdx.x;
    int n2 = n_elem * n_elem;
    for (int i = tid; i < n2; i += 256) pt[i] = ptab_g[i];
    __syncthreads();

    const float inv_rmax = 1.0f / rmax_ptr[0];
    int t = blockIdx.x * blockDim.x + tid;
    int base = t * 4;
    if (base >= total) return;
    int nb2 = 2 * nb;

    if (vec_ok && base + 3 < n_edges) {
        float4 L  = *reinterpret_cast<const float4*>(lengths + base);
        int4   S4 = *reinterpret_cast<const int4*>(src + base);
        int4   D4 = *reinterpret_cast<const int4*>(dst + base);
        int sv[4] = {S4.x, S4.y, S4.z, S4.w};
        int dv[4] = {D4.x, D4.y, D4.z, D4.w};
        float lv[4] = {L.x, L.y, L.z, L.w};
        int spi[4], spj[4];
#pragma unroll
        for (int k = 0; k < 4; ++k) {
            spi[k] = spec[sv[k]];
            spj[k] = spec[dv[k]];
        }
        unsigned long long rv[4];
#pragma unroll
        for (int k = 0; k < 4; ++k) {
            float2 c = pt[spi[k] * n_elem + spj[k]];
            float q = edge_energy_pt(lv[k], c, inv_rmax);
            uint32_t qu = __float_as_uint(q) >> qshift;
            rv[k] = (unsigned long long)(unsigned)sv[k]
                  | ((unsigned long long)(unsigned)dv[k] << nb)
                  | ((unsigned long long)qu << nb2);
        }
        uint4* out = reinterpret_cast<uint4*>(recs + base);
        out[0] = make_uint4((uint32_t)rv[0], (uint32_t)(rv[0] >> 32),
                            (uint32_t)rv[1], (uint32_t)(rv[1] >> 32));
        out[1] = make_uint4((uint32_t)rv[2], (uint32_t)(rv[2] >> 32),
                            (uint32_t)rv[3], (uint32_t)(rv[3] >> 32));
    } else {
        for (int k = 0; k < 4; ++k) {
            int e = base + k;
            if (e >= total) break;
            unsigned long long rec = 0ull;
            if (e < n_edges) {
                int si = src[e], di = dst[e];
                float2 c = pt[spec[si] * n_elem + spec[di]];
                float q = edge_energy_pt(lengths[e], c, inv_rmax);
                uint32_t qu = __float_as_uint(q) >> qshift;
                rec = (unsigned long long)(unsigned)si
                    | ((unsigned long long)(unsigned)di << nb)
                    | ((unsigned long long)qu << (2 * nb));
            }
            recs[e] = rec;
        }
    }
}

// ------------------------------------------- fallback accum (R11, f32 LDS)
__device__ __forceinline__ void accum_rec(
    unsigned long long rec, float* __restrict__ acc,
    unsigned base, unsigned nmask, int nb, int nb2, int qshift, unsigned nr) {
    unsigned sn = (unsigned)rec & nmask;
    unsigned dn = (unsigned)(rec >> nb) & nmask;
    float q = __uint_as_float((uint32_t)(rec >> nb2) << qshift);
    unsigned a = sn - base;
    if (a < nr) atomicAdd(&acc[a], q);
    unsigned b = dn - base;
    if (b < nr) atomicAdd(&acc[b], q);
}

__global__ __launch_bounds__(512) void accum_kernel(
    const unsigned long long* __restrict__ recs,
    uint16_t* __restrict__ partial,      // S rows of npad bf16
    int n_edges, int S, int EPB, int npad, int nb, int qshift) {
    __shared__ float acc[NR];
    int tid = threadIdx.x;
    for (int i = tid; i < NR; i += 512) acc[i] = 0.0f;
    __syncthreads();

    int s = blockIdx.x % S;
    int p = blockIdx.x / S;
    const unsigned base = (unsigned)p * NR;
    const unsigned nmask = (1u << nb) - 1u;
    const int nb2 = 2 * nb;

    int e0 = s * EPB;
    int e1 = min(e0 + EPB, n_edges);

    for (int off = e0 + tid * 8; off < e1; off += 512 * 8) {
        if (off + 8 <= e1) {
            uint4 r0 = *reinterpret_cast<const uint4*>(recs + off);
            uint4 r1 = *reinterpret_cast<const uint4*>(recs + off + 2);
            uint4 r2 = *reinterpret_cast<const uint4*>(recs + off + 4);
            uint4 r3 = *reinterpret_cast<const uint4*>(recs + off + 6);
            uint4 rr[4] = {r0, r1, r2, r3};
#pragma unroll
            for (int k = 0; k < 4; ++k) {
                unsigned long long ra = (unsigned long long)rr[k].x
                                      | ((unsigned long long)rr[k].y << 32);
                unsigned long long rb = (unsigned long long)rr[k].z
                                      | ((unsigned long long)rr[k].w << 32);
                accum_rec(ra, acc, base, nmask, nb, nb2, qshift, NR);
                accum_rec(rb, acc, base, nmask, nb, nb2, qshift, NR);
            }
        } else {
            for (int e = off; e < e1; ++e)
                accum_rec(recs[e], acc, base, nmask, nb, nb2, qshift, NR);
        }
    }
    __syncthreads();

    uint16_t* __restrict__ row = partial + (size_t)s * npad + base;
    for (int i = tid; i < NR; i += 512)
        row[i] = f32_to_bf16_rne(acc[i]);
}

__global__ void combine_kernel(const uint16_t* __restrict__ partial,
                               float* __restrict__ out,
                               int n_nodes, int S, int npad) {
    int i = blockIdx.x * blockDim.x + threadIdx.x;
    if (i >= n_nodes) return;
    float t = 0.0f;
    for (int s = 0; s < S; ++s) {
        uint32_t h = partial[(size_t)s * npad + i];
        t += __uint_as_float(h << 16);
    }
    out[i] = t;
}

// ----------------------------------------------------------- fallback (R2)
__global__ void zero_out_kernel(float* __restrict__ out, int n) {
    int i = blockIdx.x * blockDim.x + threadIdx.x;
    if (i < n) out[i] = 0.0f;
}

__global__ __launch_bounds__(256) void edge_kernel_atomic(
    const float* __restrict__ lengths,
    const int* __restrict__ src_idx,
    const int* __restrict__ dst_idx,
    const float2* __restrict__ ztab,
    const float* __restrict__ rmax_ptr,
    float* __restrict__ out,
    int n_edges) {
    const float inv_rmax = 1.0f / rmax_ptr[0];
    int t = blockIdx.x * blockDim.x + threadIdx.x;
    int base = t * 4;
    if (base + 3 < n_edges) {
        float4 L = *reinterpret_cast<const float4*>(lengths + base);
        int4 S = *reinterpret_cast<const int4*>(src_idx + base);
        int4 D = *reinterpret_cast<const int4*>(dst_idx + base);
        float l[4] = {L.x, L.y, L.z, L.w};
        int s[4] = {S.x, S.y, S.z, S.w};
        int d[4] = {D.x, D.y, D.z, D.w};
        float2 zs[4], zd[4];
#pragma unroll
        for (int k = 0; k < 4; ++k) { zs[k] = ztab[s[k]]; zd[k] = ztab[d[k]]; }
#pragma unroll
        for (int k = 0; k < 4; ++k) {
            float q = edge_energy(l[k], zs[k], zd[k], inv_rmax);
            unsafeAtomicAdd(&out[s[k]], q);
            unsafeAtomicAdd(&out[d[k]], q);
        }
    } else if (base < n_edges) {
        for (int e = base; e < n_edges; ++e) {
            int si = src_idx[e], di = dst_idx[e];
            float q = edge_energy(lengths[e], ztab[si], ztab[di], inv_rmax);
            unsafeAtomicAdd(&out[si], q);
            unsafeAtomicAdd(&out[di], q);
        }
    }
}

// ---------------------------------------------------------------- launcher
extern "C" void kernel_launch(void* const* d_in, const int* in_sizes, int n_in,
                              void* d_out, int out_size, void* d_ws, size_t ws_size,
                              hipStream_t stream) {
    const float* lengths        = (const float*)d_in[0];
    const float* node_attrs     = (const float*)d_in[1];
    const int*   edge_index     = (const int*)d_in[2];
    const float* atomic_numbers = (const float*)d_in[3];
    const float* rmax_ptr       = (const float*)d_in[4];

    int n_edges = in_sizes[0];
    int n_elem  = in_sizes[3];
    int n_nodes = out_size;
    float* out = (float*)d_out;

    const int* src = edge_index;
    const int* dst = edge_index + n_edges;

    int vec_ok = ((n_edges & 3) == 0) ? 1 : 0;

    int nb_nodes = (n_nodes + 255) / 256;
    int spec_bytes = (n_nodes + 3) & ~3;

    // -------- one-time dynamic-LDS opt-ins (host-side, capture-safe)
    static int accq_ok = -1;
    if (accq_ok < 0) {
        accq_ok = (hipFuncSetAttribute(
                       reinterpret_cast<const void*>(accum_q_kernel),
                       hipFuncAttributeMaxDynamicSharedMemorySize,
                       NRQ * 4) == hipSuccess) ? 1 : 0;
    }
    static int pack_lds_ok = -1;
    if (pack_lds_ok < 0) {
        pack_lds_ok = (hipFuncSetAttribute(
                           reinterpret_cast<const void*>(energy_q_lds_kernel),
                           hipFuncAttributeMaxDynamicSharedMemorySize,
                           LDS_SPEC_MAX) == hipSuccess) ? 1 : 0;
    }

    // -------- R16 path: q-only fp16 intermediate, direct src/dst accum
    if (accq_ok && pack_lds_ok && (spec_bytes <= LDS_SPEC_MAX)
        && (n_elem * n_elem <= PT_MAX)) {
        int P    = (n_nodes + NRQ - 1) / NRQ;      // 4 for n_nodes=100K
        int npad = P * NRQ;
        int S = (256 / P) & ~7;
        if (S < 8) S = 8;
        size_t part_off = 0, ptab_off = 0, spec_off = 0, need = 0;
        int EPB = 0;
        for (; S >= 8; S -= 8) {
            EPB = (((n_edges + S - 1) / S) + 4095) & ~4095;   // mult of 4096
            size_t q_bytes = ((size_t)n_edges * 2 + 255) & ~(size_t)255;
            part_off = q_bytes;
            ptab_off = (part_off + (size_t)S * npad * 2 + 255) & ~(size_t)255;
            spec_off = (ptab_off + (size_t)n_elem * n_elem * 8 + 255) & ~(size_t)255;
            need     = spec_off + (size_t)spec_bytes;
            if (need <= ws_size) break;
        }
        if (S >= 8) {
            __half*   qarr    = (__half*)d_ws;
            uint16_t* partial = (uint16_t*)((char*)d_ws + part_off);
            float2*   ptab    = (float2*)((char*)d_ws + ptab_off);
            uint8_t*  spec    = (uint8_t*)((char*)d_ws + spec_off);

            species_kernel<<<nb_nodes, 256, 0, stream>>>(
                node_attrs, spec, n_nodes, n_elem);
            pair_kernel<<<1, PT_MAX, 0, stream>>>(atomic_numbers, ptab, n_elem);
            int chunk = (((n_edges + 255) / 256) + 3) & ~3;   // x4
            energy_q_lds_kernel<<<256, 1024, spec_bytes, stream>>>(
                lengths, src, dst, spec, ptab, rmax_ptr, qarr,
                n_edges, n_nodes, n_elem, chunk);
            accum_q_kernel<<<P * S, 1024, NRQ * 4, stream>>>(
                src, dst, qarr, partial, n_edges, S, EPB, npad);
            combine_kernel<<<nb_nodes, 256, 0, stream>>>(
                partial, out, n_nodes, S, npad);
            return;
        }
    }

    // -------- R11 path: 8B records, 50KB static LDS accum
    {
        int nb = 1;
        while ((1u << nb) < (unsigned)n_nodes) nb++;
        int qb = 64 - 2 * nb;
        if (qb > 32) qb = 32;
        int qshift = 32 - qb;
        bool pack_ok = (2 * nb + 16 <= 64) && (n_elem * n_elem <= PT_MAX);

        if (pack_ok) {
            int P    = (n_nodes + NR - 1) / NR;
            int npad = P * NR;
            int S = (768 / P) & ~7;
            if (S < 8) S = 8;
            size_t part_off = 0, ptab_off = 0, spec_off = 0, need = 0;
            int EPB = 0, TOTAL = 0;
            for (; S >= 8; S -= 8) {
                EPB = (((n_edges + S - 1) / S) + 4095) & ~4095;
                TOTAL = S * EPB;
                part_off = ((size_t)TOTAL * 8 + 255) & ~(size_t)255;
                ptab_off = (part_off + (size_t)S * npad * 2 + 255) & ~(size_t)255;
                spec_off = (ptab_off + (size_t)n_elem * n_elem * 8 + 255) & ~(size_t)255;
                need     = spec_off + (size_t)spec_bytes;
                if (need <= ws_size) break;
            }
            if (S >= 8) {
                unsigned long long* recs = (unsigned long long*)d_ws;
                uint16_t* partial = (uint16_t*)((char*)d_ws + part_off);
                float2*   ptab    = (float2*)((char*)d_ws + ptab_off);
                uint8_t*  spec    = (uint8_t*)((char*)d_ws + spec_off);

                species_kernel<<<nb_nodes, 256, 0, stream>>>(
                    node_attrs, spec, n_nodes, n_elem);
                pair_kernel<<<1, PT_MAX, 0, stream>>>(atomic_numbers, ptab, n_elem);
                int nb_energy = TOTAL / 1024;
                energy_pack_kernel<<<nb_energy, 256, 0, stream>>>(
                    lengths, src, dst, spec, ptab, rmax_ptr, recs,
                    n_edges, TOTAL, n_elem, nb, qshift, vec_ok);
                accum_kernel<<<P * S, 512, 0, stream>>>(
                    recs, partial, n_edges, S, EPB, npad, nb, qshift);
                combine_kernel<<<nb_nodes, 256, 0, stream>>>(
                    partial, out, n_nodes, S, npad);
                return;
            }
        }
    }

    // -------- fallback: replicated-atomic path (R2)
    {
        int stride = ((n_nodes + 49) / 2) * 2;
        int R = 16;
        while (R > 1 &&
               (size_t)R * stride * sizeof(float) + (size_t)n_nodes * sizeof(float2)
                   > ws_size)
            R >>= 1;
        float2* ztab = (float2*)((char*)d_ws + (size_t)R * stride * sizeof(float));
        hipMemsetAsync(d_ws, 0, (size_t)R * stride * sizeof(float), stream);
        prep_nodes_kernel<<<nb_nodes, 256, 0, stream>>>(
            node_attrs, atomic_numbers, ztab, n_nodes, n_elem);
        zero_out_kernel<<<nb_nodes, 256, 0, stream>>>(out, n_nodes);
        int n_thread4 = (n_edges + 3) / 4;
        int nb_edges = (n_thread4 + 255) / 256;
        edge_kernel_atomic<<<nb_edges, 256, 0, stream>>>(
            lengths, src, dst, ztab, rmax_ptr, out, n_edges);
    }
}

// Round 7
// 153.440 us; speedup vs baseline: 1.6102x; 1.0040x over previous
//
#include <hip/hip_runtime.h>
#include <hip/hip_bf16.h>
#include <hip/hip_fp16.h>
#include <stdint.h>

// ---------------------------------------------------------------------------
// PairRepulsionSwitch: per-edge ZBL + r^-12 repulsion, quarter-summed to both
// endpoint nodes.
//
// R1-R9: atomics rate-limit (655us) -> binning -> LDS sort -> multipass LDS
//   accum -> split energy/accum (252us).
// R10/R11: species trick + 8B packed records; clamp scan to n_edges.
// R12: 100KB LDS accumulator, 1 blk/CU. Traffic halved, time unchanged.
// R13: unsafeAtomicAdd null (hipcc already emits ds_add_f32).
// R14: WIN: fixed-point i32 accumulator -> ds_add_u32 is bank-parallel
//   (f32 LDS atomics serialize ~3.6cy/lane). 239 -> 187us.
// R15: WIN: persistent pack, spec table in 100KB LDS. 187 -> 164us.
// R16: WIN: killed the 8B recs round-trip; energy writes only fp16 q
//   (2B/edge), accum reads src/dst/q directly. 164 -> 154us. Top-5 is now
//   ONLY the harness's 256MB re-poison fill (40us @83% HBM = optimal).
// R17: last structural redundancy: P=4 accum passes re-scan all
//   (src,dst,q) 4x (L2-resident, issue-bound). NRQ 32768 -> 36864
//   (144KB i32 LDS, still 1 blk/CU) -> P=3, S=80, grid=240: deletes one
//   full scan pass (-64MB L2 reads, -25% accum issue work). Accum inner
//   loop widened to 8 edges/iter (16B q loads). If this lands <2us,
//   the pipeline is at its structural floor vs the ~90us fixed harness
//   overhead -> roofline.
// ---------------------------------------------------------------------------

#define KE_CONST 14.3996454784255f
constexpr float INV_AC = 1.0f / (0.88534f * 0.52917721092f);

#define NR 12800             // R11 fallback: nodes per range (50 KB static)
#define NRQ 36864            // R17 path: nodes per range (144 KB i32 LDS)
#define PT_MAX 256           // max n_elem^2 pair-table entries
#define LDS_SPEC_MAX 147456  // max dynamic LDS bytes for spec table (144 KB)

#define QSCALE 4096.0f       // fixed-point scale for i32 LDS accumulation
#define QINV   (1.0f / 4096.0f)

// ---------------------------------------------------------------- shared math
// c.x = KE*Zi*Zj*SCALE, c.y = (Zi^0.23 + Zj^0.23) * INV_AC
__device__ __forceinline__ float edge_energy_pt(float len, float2 c,
                                                float inv_rmax) {
    float r = fmaxf(len, 0.2f);                 // R_MIN clamp
    float inv_r = 1.0f / r;

    float u = fmaxf(1.0f - r * inv_rmax, 0.0f);
    float u2 = u * u;
    float pc = u2 * u2 * u2;                    // (1-x)^6

    float x = r * c.y;
    float phi = 0.1818f   * __expf(-3.2f    * x)
              + 0.5099f   * __expf(-0.9423f * x)
              + 0.2802f   * __expf(-0.4029f * x)
              + 0.02817f  * __expf(-0.2016f * x);
    float v_zbl = c.x * phi * inv_r * pc;

    float ir2 = inv_r * inv_r;
    float ir4 = ir2 * ir2;
    float ir12 = ir4 * ir4 * ir4;
    float t = fminf(fmaxf((1.5f - r) * 5.0f, 0.0f), 1.0f);
    float sm = t * t * (3.0f - 2.0f * t);
    float v_r12 = 1e-4f * ir12 * pc * sm;

    return 0.25f * (v_zbl + v_r12);
}

__device__ __forceinline__ float edge_energy(float len, float2 zi, float2 zj,
                                             float inv_rmax) {
    float2 c = make_float2(KE_CONST * zi.x * zj.x, (zi.y + zj.y) * INV_AC);
    return edge_energy_pt(len, c, inv_rmax);
}

__device__ __forceinline__ uint16_t f32_to_bf16_rne(float v) {
    uint32_t u = __float_as_uint(v);
    u += 0x7FFFu + ((u >> 16) & 1u);
    return (uint16_t)(u >> 16);
}

// ---------------------------------------------------------------- prep
__global__ void species_kernel(const float* __restrict__ node_attrs,
                               uint8_t* __restrict__ spec,
                               int n_nodes, int n_elem) {
    int i = blockIdx.x * blockDim.x + threadIdx.x;
    if (i >= n_nodes) return;
    float v = 0.0f;
    for (int k = 0; k < n_elem; ++k)
        v += node_attrs[i * n_elem + k] * (float)k;
    spec[i] = (uint8_t)(v + 0.5f);
}

__global__ void pair_kernel(const float* __restrict__ atomic_numbers,
                            float2* __restrict__ ptab, int n_elem) {
    int idx = threadIdx.x;
    int n2 = n_elem * n_elem;
    if (idx >= n2) return;
    int i = idx / n_elem, j = idx % n_elem;
    float Zi = atomic_numbers[i], Zj = atomic_numbers[j];
    ptab[idx] = make_float2(KE_CONST * Zi * Zj,
                            (powf(Zi, 0.23f) + powf(Zj, 0.23f)) * INV_AC);
}

__global__ void prep_nodes_kernel(const float* __restrict__ node_attrs,
                                  const float* __restrict__ atomic_numbers,
                                  float2* __restrict__ ztab,
                                  int n_nodes, int n_elem) {
    int i = blockIdx.x * blockDim.x + threadIdx.x;
    if (i >= n_nodes) return;
    float z = 0.0f;
    for (int k = 0; k < n_elem; ++k)
        z += node_attrs[i * n_elem + k] * atomic_numbers[k];
    ztab[i] = make_float2(z, powf(z, 0.23f));
}

// ------------------- R16: persistent energy kernel, spec in LDS, q out fp16
// 256 blocks x 1024 threads (1 blk/CU). Dynamic LDS = spec table.
__global__ __launch_bounds__(1024) void energy_q_lds_kernel(
    const float* __restrict__ lengths,
    const int* __restrict__ src, const int* __restrict__ dst,
    const uint8_t* __restrict__ spec,
    const float2* __restrict__ ptab_g,
    const float* __restrict__ rmax_ptr,
    __half* __restrict__ qout,
    int n_edges, int n_nodes, int n_elem, int chunk) {
    extern __shared__ uint8_t lsp[];     // n_nodes bytes (4B-padded)
    __shared__ float2 pt[PT_MAX];
    int tid = threadIdx.x;

    int n2 = n_elem * n_elem;
    for (int i = tid; i < n2; i += 1024) pt[i] = ptab_g[i];
    {
        int nw = (n_nodes + 3) >> 2;
        const uint32_t* s32 = reinterpret_cast<const uint32_t*>(spec);
        uint32_t* l32 = reinterpret_cast<uint32_t*>(lsp);
        for (int i = tid; i < nw; i += 1024) l32[i] = s32[i];
    }
    __syncthreads();

    const float inv_rmax = 1.0f / rmax_ptr[0];
    int e0 = blockIdx.x * chunk;
    int e1 = min(e0 + chunk, n_edges);

    for (int base = e0 + tid * 4; base < e1; base += 1024 * 4) {
        if (base + 4 <= e1) {            // chunk,e0 mult of 4 -> aligned
            float4 L  = *reinterpret_cast<const float4*>(lengths + base);
            int4   S4 = *reinterpret_cast<const int4*>(src + base);
            int4   D4 = *reinterpret_cast<const int4*>(dst + base);
            int sv[4] = {S4.x, S4.y, S4.z, S4.w};
            int dv[4] = {D4.x, D4.y, D4.z, D4.w};
            float lv[4] = {L.x, L.y, L.z, L.w};
            int spi[4], spj[4];
#pragma unroll
            for (int k = 0; k < 4; ++k) {       // LDS gathers (ds_read_u8)
                spi[k] = lsp[sv[k]];
                spj[k] = lsp[dv[k]];
            }
            float q[4];
#pragma unroll
            for (int k = 0; k < 4; ++k) {
                float2 c = pt[spi[k] * n_elem + spj[k]];
                q[k] = edge_energy_pt(lv[k], c, inv_rmax);
            }
            __half2 h01 = __floats2half2_rn(q[0], q[1]);
            __half2 h23 = __floats2half2_rn(q[2], q[3]);
            uint32_t w0, w1;
            memcpy(&w0, &h01, 4);
            memcpy(&w1, &h23, 4);
            *reinterpret_cast<uint2*>(qout + base) = make_uint2(w0, w1);
        } else {
            for (int e = base; e < e1; ++e) {
                int si = src[e], di = dst[e];
                float2 c = pt[lsp[si] * n_elem + lsp[di]];
                qout[e] = __float2half_rn(edge_energy_pt(lengths[e], c, inv_rmax));
            }
        }
    }
}

// ------------------- R17: accumulate straight from src/dst/q (no records)
// grid = P*S, 1024 threads, dynamic LDS = NRQ i32 (144KB, 1 blk/CU).
// 8 edges/iter (two int4 pairs + one uint4 of 8 halves).
__global__ __launch_bounds__(1024) void accum_q_kernel(
    const int* __restrict__ src, const int* __restrict__ dst,
    const __half* __restrict__ qv,
    uint16_t* __restrict__ partial,      // S rows of npad bf16
    int n_edges, int S, int EPB, int npad) {
    extern __shared__ int acc[];
    int tid = threadIdx.x;
    const int4 z4 = make_int4(0, 0, 0, 0);
    for (int i = tid * 4; i < NRQ; i += 1024 * 4)
        *reinterpret_cast<int4*>(acc + i) = z4;
    __syncthreads();

    int s = blockIdx.x % S;              // S%8==0: same-s blocks -> same XCD
    int p = blockIdx.x / S;
    const unsigned base = (unsigned)p * NRQ;

    int e0 = s * EPB;                    // EPB mult of 4096 -> aligned loads
    int e1 = min(e0 + EPB, n_edges);

    for (int off = e0 + tid * 8; off < e1; off += 1024 * 8) {
        if (off + 8 <= e1) {
            int4 Sa = *reinterpret_cast<const int4*>(src + off);
            int4 Sb = *reinterpret_cast<const int4*>(src + off + 4);
            int4 Da = *reinterpret_cast<const int4*>(dst + off);
            int4 Db = *reinterpret_cast<const int4*>(dst + off + 4);
            uint4 Q4 = *reinterpret_cast<const uint4*>(qv + off);  // 8 halves
            const __half2* hq = reinterpret_cast<const __half2*>(&Q4);
            int sv[8] = {Sa.x, Sa.y, Sa.z, Sa.w, Sb.x, Sb.y, Sb.z, Sb.w};
            int dv[8] = {Da.x, Da.y, Da.z, Da.w, Db.x, Db.y, Db.z, Db.w};
            float qf[8];
#pragma unroll
            for (int k = 0; k < 4; ++k) {
                qf[2 * k]     = __low2float(hq[k]);
                qf[2 * k + 1] = __high2float(hq[k]);
            }
#pragma unroll
            for (int k = 0; k < 8; ++k) {
                int qi = __float2int_rn(qf[k] * QSCALE);
                unsigned a = (unsigned)sv[k] - base;
                if (a < NRQ) atomicAdd(&acc[a], qi);
                unsigned b = (unsigned)dv[k] - base;
                if (b < NRQ) atomicAdd(&acc[b], qi);
            }
        } else {
            for (int e = off; e < e1; ++e) {
                int qi = __float2int_rn(__half2float(qv[e]) * QSCALE);
                unsigned a = (unsigned)src[e] - base;
                if (a < NRQ) atomicAdd(&acc[a], qi);
                unsigned b = (unsigned)dst[e] - base;
                if (b < NRQ) atomicAdd(&acc[b], qi);
            }
        }
    }
    __syncthreads();

    // vectorized bf16 flush: 4 ints -> f32 -> 8B store
    uint16_t* __restrict__ row = partial + (size_t)s * npad + base;
    for (int i = tid * 4; i < NRQ; i += 1024 * 4) {
        int4 v = *reinterpret_cast<const int4*>(acc + i);
        float f0 = (float)v.x * QINV, f1 = (float)v.y * QINV;
        float f2 = (float)v.z * QINV, f3 = (float)v.w * QINV;
        uint32_t w0 = (uint32_t)f32_to_bf16_rne(f0)
                    | ((uint32_t)f32_to_bf16_rne(f1) << 16);
        uint32_t w1 = (uint32_t)f32_to_bf16_rne(f2)
                    | ((uint32_t)f32_to_bf16_rne(f3) << 16);
        *reinterpret_cast<uint2*>(row + i) = make_uint2(w0, w1);
    }
}

// ---------------- fallback pack (R10/R11): global spec gathers, 8B records
__global__ __launch_bounds__(256) void energy_pack_kernel(
    const float* __restrict__ lengths,
    const int* __restrict__ src, const int* __restrict__ dst,
    const uint8_t* __restrict__ spec,
    const float2* __restrict__ ptab_g,
    const float* __restrict__ rmax_ptr,
    unsigned long long* __restrict__ recs,
    int n_edges, int total, int n_elem, int nb, int qshift, int vec_ok) {
    __shared__ float2 pt[PT_MAX];
    int tid = threadIdx.x;
    int n2 = n_elem * n_elem;
    for (int i = tid; i < n2; i += 256) pt[i] = ptab_g[i];
    __syncthreads();

    const float inv_rmax = 1.0f / rmax_ptr[0];
    int t = blockIdx.x * blockDim.x + tid;
    int base = t * 4;
    if (base >= total) return;
    int nb2 = 2 * nb;

    if (vec_ok && base + 3 < n_edges) {
        float4 L  = *reinterpret_cast<const float4*>(lengths + base);
        int4   S4 = *reinterpret_cast<const int4*>(src + base);
        int4   D4 = *reinterpret_cast<const int4*>(dst + base);
        int sv[4] = {S4.x, S4.y, S4.z, S4.w};
        int dv[4] = {D4.x, D4.y, D4.z, D4.w};
        float lv[4] = {L.x, L.y, L.z, L.w};
        int spi[4], spj[4];
#pragma unroll
        for (int k = 0; k < 4; ++k) {
            spi[k] = spec[sv[k]];
            spj[k] = spec[dv[k]];
        }
        unsigned long long rv[4];
#pragma unroll
        for (int k = 0; k < 4; ++k) {
            float2 c = pt[spi[k] * n_elem + spj[k]];
            float q = edge_energy_pt(lv[k], c, inv_rmax);
            uint32_t qu = __float_as_uint(q) >> qshift;
            rv[k] = (unsigned long long)(unsigned)sv[k]
                  | ((unsigned long long)(unsigned)dv[k] << nb)
                  | ((unsigned long long)qu << nb2);
        }
        uint4* out = reinterpret_cast<uint4*>(recs + base);
        out[0] = make_uint4((uint32_t)rv[0], (uint32_t)(rv[0] >> 32),
                            (uint32_t)rv[1], (uint32_t)(rv[1] >> 32));
        out[1] = make_uint4((uint32_t)rv[2], (uint32_t)(rv[2] >> 32),
                            (uint32_t)rv[3], (uint32_t)(rv[3] >> 32));
    } else {
        for (int k = 0; k < 4; ++k) {
            int e = base + k;
            if (e >= total) break;
            unsigned long long rec = 0ull;
            if (e < n_edges) {
                int si = src[e], di = dst[e];
                float2 c = pt[spec[si] * n_elem + spec[di]];
                float q = edge_energy_pt(lengths[e], c, inv_rmax);
                uint32_t qu = __float_as_uint(q) >> qshift;
                rec = (unsigned long long)(unsigned)si
                    | ((unsigned long long)(unsigned)di << nb)
                    | ((unsigned long long)qu << (2 * nb));
            }
            recs[e] = rec;
        }
    }
}

// ------------------------------------------- fallback accum (R11, f32 LDS)
__device__ __forceinline__ void accum_rec(
    unsigned long long rec, float* __restrict__ acc,
    unsigned base, unsigned nmask, int nb, int nb2, int qshift, unsigned nr) {
    unsigned sn = (unsigned)rec & nmask;
    unsigned dn = (unsigned)(rec >> nb) & nmask;
    float q = __uint_as_float((uint32_t)(rec >> nb2) << qshift);
    unsigned a = sn - base;
    if (a < nr) atomicAdd(&acc[a], q);
    unsigned b = dn - base;
    if (b < nr) atomicAdd(&acc[b], q);
}

__global__ __launch_bounds__(512) void accum_kernel(
    const unsigned long long* __restrict__ recs,
    uint16_t* __restrict__ partial,      // S rows of npad bf16
    int n_edges, int S, int EPB, int npad, int nb, int qshift) {
    __shared__ float acc[NR];
    int tid = threadIdx.x;
    for (int i = tid; i < NR; i += 512) acc[i] = 0.0f;
    __syncthreads();

    int s = blockIdx.x % S;
    int p = blockIdx.x / S;
    const unsigned base = (unsigned)p * NR;
    const unsigned nmask = (1u << nb) - 1u;
    const int nb2 = 2 * nb;

    int e0 = s * EPB;
    int e1 = min(e0 + EPB, n_edges);

    for (int off = e0 + tid * 8; off < e1; off += 512 * 8) {
        if (off + 8 <= e1) {
            uint4 r0 = *reinterpret_cast<const uint4*>(recs + off);
            uint4 r1 = *reinterpret_cast<const uint4*>(recs + off + 2);
            uint4 r2 = *reinterpret_cast<const uint4*>(recs + off + 4);
            uint4 r3 = *reinterpret_cast<const uint4*>(recs + off + 6);
            uint4 rr[4] = {r0, r1, r2, r3};
#pragma unroll
            for (int k = 0; k < 4; ++k) {
                unsigned long long ra = (unsigned long long)rr[k].x
                                      | ((unsigned long long)rr[k].y << 32);
                unsigned long long rb = (unsigned long long)rr[k].z
                                      | ((unsigned long long)rr[k].w << 32);
                accum_rec(ra, acc, base, nmask, nb, nb2, qshift, NR);
                accum_rec(rb, acc, base, nmask, nb, nb2, qshift, NR);
            }
        } else {
            for (int e = off; e < e1; ++e)
                accum_rec(recs[e], acc, base, nmask, nb, nb2, qshift, NR);
        }
    }
    __syncthreads();

    uint16_t* __restrict__ row = partial + (size_t)s * npad + base;
    for (int i = tid; i < NR; i += 512)
        row[i] = f32_to_bf16_rne(acc[i]);
}

__global__ void combine_kernel(const uint16_t* __restrict__ partial,
                               float* __restrict__ out,
                               int n_nodes, int S, int npad) {
    int i = blockIdx.x * blockDim.x + threadIdx.x;
    if (i >= n_nodes) return;
    float t = 0.0f;
    for (int s = 0; s < S; ++s) {
        uint32_t h = partial[(size_t)s * npad + i];
        t += __uint_as_float(h << 16);
    }
    out[i] = t;
}

// ----------------------------------------------------------- fallback (R2)
__global__ void zero_out_kernel(float* __restrict__ out, int n) {
    int i = blockIdx.x * blockDim.x + threadIdx.x;
    if (i < n) out[i] = 0.0f;
}

__global__ __launch_bounds__(256) void edge_kernel_atomic(
    const float* __restrict__ lengths,
    const int* __restrict__ src_idx,
    const int* __restrict__ dst_idx,
    const float2* __restrict__ ztab,
    const float* __restrict__ rmax_ptr,
    float* __restrict__ out,
    int n_edges) {
    const float inv_rmax = 1.0f / rmax_ptr[0];
    int t = blockIdx.x * blockDim.x + threadIdx.x;
    int base = t * 4;
    if (base + 3 < n_edges) {
        float4 L = *reinterpret_cast<const float4*>(lengths + base);
        int4 S = *reinterpret_cast<const int4*>(src_idx + base);
        int4 D = *reinterpret_cast<const int4*>(dst_idx + base);
        float l[4] = {L.x, L.y, L.z, L.w};
        int s[4] = {S.x, S.y, S.z, S.w};
        int d[4] = {D.x, D.y, D.z, D.w};
        float2 zs[4], zd[4];
#pragma unroll
        for (int k = 0; k < 4; ++k) { zs[k] = ztab[s[k]]; zd[k] = ztab[d[k]]; }
#pragma unroll
        for (int k = 0; k < 4; ++k) {
            float q = edge_energy(l[k], zs[k], zd[k], inv_rmax);
            unsafeAtomicAdd(&out[s[k]], q);
            unsafeAtomicAdd(&out[d[k]], q);
        }
    } else if (base < n_edges) {
        for (int e = base; e < n_edges; ++e) {
            int si = src_idx[e], di = dst_idx[e];
            float q = edge_energy(lengths[e], ztab[si], ztab[di], inv_rmax);
            unsafeAtomicAdd(&out[si], q);
            unsafeAtomicAdd(&out[di], q);
        }
    }
}

// ---------------------------------------------------------------- launcher
extern "C" void kernel_launch(void* const* d_in, const int* in_sizes, int n_in,
                              void* d_out, int out_size, void* d_ws, size_t ws_size,
                              hipStream_t stream) {
    const float* lengths        = (const float*)d_in[0];
    const float* node_attrs     = (const float*)d_in[1];
    const int*   edge_index     = (const int*)d_in[2];
    const float* atomic_numbers = (const float*)d_in[3];
    const float* rmax_ptr       = (const float*)d_in[4];

    int n_edges = in_sizes[0];
    int n_elem  = in_sizes[3];
    int n_nodes = out_size;
    float* out = (float*)d_out;

    const int* src = edge_index;
    const int* dst = edge_index + n_edges;

    int vec_ok = ((n_edges & 3) == 0) ? 1 : 0;

    int nb_nodes = (n_nodes + 255) / 256;
    int spec_bytes = (n_nodes + 3) & ~3;

    // -------- one-time dynamic-LDS opt-ins (host-side, capture-safe)
    static int accq_ok = -1;
    if (accq_ok < 0) {
        accq_ok = (hipFuncSetAttribute(
                       reinterpret_cast<const void*>(accum_q_kernel),
                       hipFuncAttributeMaxDynamicSharedMemorySize,
                       NRQ * 4) == hipSuccess) ? 1 : 0;
    }
    static int pack_lds_ok = -1;
    if (pack_lds_ok < 0) {
        pack_lds_ok = (hipFuncSetAttribute(
                           reinterpret_cast<const void*>(energy_q_lds_kernel),
                           hipFuncAttributeMaxDynamicSharedMemorySize,
                           LDS_SPEC_MAX) == hipSuccess) ? 1 : 0;
    }

    // -------- R17 path: fp16 q intermediate, direct src/dst accum, P=3
    if (accq_ok && pack_lds_ok && (spec_bytes <= LDS_SPEC_MAX)
        && (n_elem * n_elem <= PT_MAX)) {
        int P    = (n_nodes + NRQ - 1) / NRQ;      // 3 for n_nodes=100K
        int npad = P * NRQ;
        int S = (256 / P) & ~7;
        if (S < 8) S = 8;
        size_t part_off = 0, ptab_off = 0, spec_off = 0, need = 0;
        int EPB = 0;
        for (; S >= 8; S -= 8) {
            EPB = (((n_edges + S - 1) / S) + 4095) & ~4095;   // mult of 4096
            size_t q_bytes = ((size_t)n_edges * 2 + 255) & ~(size_t)255;
            part_off = q_bytes;
            ptab_off = (part_off + (size_t)S * npad * 2 + 255) & ~(size_t)255;
            spec_off = (ptab_off + (size_t)n_elem * n_elem * 8 + 255) & ~(size_t)255;
            need     = spec_off + (size_t)spec_bytes;
            if (need <= ws_size) break;
        }
        if (S >= 8) {
            __half*   qarr    = (__half*)d_ws;
            uint16_t* partial = (uint16_t*)((char*)d_ws + part_off);
            float2*   ptab    = (float2*)((char*)d_ws + ptab_off);
            uint8_t*  spec    = (uint8_t*)((char*)d_ws + spec_off);

            species_kernel<<<nb_nodes, 256, 0, stream>>>(
                node_attrs, spec, n_nodes, n_elem);
            pair_kernel<<<1, PT_MAX, 0, stream>>>(atomic_numbers, ptab, n_elem);
            int chunk = (((n_edges + 255) / 256) + 3) & ~3;   // x4
            energy_q_lds_kernel<<<256, 1024, spec_bytes, stream>>>(
                lengths, src, dst, spec, ptab, rmax_ptr, qarr,
                n_edges, n_nodes, n_elem, chunk);
            accum_q_kernel<<<P * S, 1024, NRQ * 4, stream>>>(
                src, dst, qarr, partial, n_edges, S, EPB, npad);
            combine_kernel<<<nb_nodes, 256, 0, stream>>>(
                partial, out, n_nodes, S, npad);
            return;
        }
    }

    // -------- R11 path: 8B records, 50KB static LDS accum
    {
        int nb = 1;
        while ((1u << nb) < (unsigned)n_nodes) nb++;
        int qb = 64 - 2 * nb;
        if (qb > 32) qb = 32;
        int qshift = 32 - qb;
        bool pack_ok = (2 * nb + 16 <= 64) && (n_elem * n_elem <= PT_MAX);

        if (pack_ok) {
            int P    = (n_nodes + NR - 1) / NR;
            int npad = P * NR;
            int S = (768 / P) & ~7;
            if (S < 8) S = 8;
            size_t part_off = 0, ptab_off = 0, spec_off = 0, need = 0;
            int EPB = 0, TOTAL = 0;
            for (; S >= 8; S -= 8) {
                EPB = (((n_edges + S - 1) / S) + 4095) & ~4095;
                TOTAL = S * EPB;
                part_off = ((size_t)TOTAL * 8 + 255) & ~(size_t)255;
                ptab_off = (part_off + (size_t)S * npad * 2 + 255) & ~(size_t)255;
                spec_off = (ptab_off + (size_t)n_elem * n_elem * 8 + 255) & ~(size_t)255;
                need     = spec_off + (size_t)spec_bytes;
                if (need <= ws_size) break;
            }
            if (S >= 8) {
                unsigned long long* recs = (unsigned long long*)d_ws;
                uint16_t* partial = (uint16_t*)((char*)d_ws + part_off);
                float2*   ptab    = (float2*)((char*)d_ws + ptab_off);
                uint8_t*  spec    = (uint8_t*)((char*)d_ws + spec_off);

                species_kernel<<<nb_nodes, 256, 0, stream>>>(
                    node_attrs, spec, n_nodes, n_elem);
                pair_kernel<<<1, PT_MAX, 0, stream>>>(atomic_numbers, ptab, n_elem);
                int nb_energy = TOTAL / 1024;
                energy_pack_kernel<<<nb_energy, 256, 0, stream>>>(
                    lengths, src, dst, spec, ptab, rmax_ptr, recs,
                    n_edges, TOTAL, n_elem, nb, qshift, vec_ok);
                accum_kernel<<<P * S, 512, 0, stream>>>(
                    recs, partial, n_edges, S, EPB, npad, nb, qshift);
                combine_kernel<<<nb_nodes, 256, 0, stream>>>(
                    partial, out, n_nodes, S, npad);
                return;
            }
        }
    }

    // -------- fallback: replicated-atomic path (R2)
    {
        int stride = ((n_nodes + 49) / 2) * 2;
        int R = 16;
        while (R > 1 &&
               (size_t)R * stride * sizeof(float) + (size_t)n_nodes * sizeof(float2)
                   > ws_size)
            R >>= 1;
        float2* ztab = (float2*)((char*)d_ws + (size_t)R * stride * sizeof(float));
        hipMemsetAsync(d_ws, 0, (size_t)R * stride * sizeof(float), stream);
        prep_nodes_kernel<<<nb_nodes, 256, 0, stream>>>(
            node_attrs, atomic_numbers, ztab, n_nodes, n_elem);
        zero_out_kernel<<<nb_nodes, 256, 0, stream>>>(out, n_nodes);
        int n_thread4 = (n_edges + 3) / 4;
        int nb_edges = (n_thread4 + 255) / 256;
        edge_kernel_atomic<<<nb_edges, 256, 0, stream>>>(
            lengths, src, dst, ztab, rmax_ptr, out, n_edges);
    }
}